// Round 4
// baseline (158.309 us; speedup 1.0000x reference)
//
#include <hip/hip_runtime.h>

// RuleClassifierSNN — forward only, fully fused.
//  * spike(post-reset v) == 0 always -> W_rec vanishes in forward.
//  * layer-0 drive is a V=128-entry lookup table (0.2f-folded) -> LDS.
//  * layer-1 GEMM: spikes {0,1} as i8 in LDS; W as 2-plane i8 fixed point
//    (q1 + q2/252, per-row scale); exact i32 accumulate, P=252*P1+P2 exact.
//  * One block per 16-batch tile: layer-0 chains + layer-1 MFMA + logits all
//    in-block; s0 never touches HBM. 2-stage software pipeline, 1 barrier/t.

#define T_STEPS 256
#define B_SZ    2048
#define H_SZ    128
#define V_SZ    128
#define E_SZ    64
#define C_SZ    12

typedef __attribute__((ext_vector_type(4))) int   i32x4;
typedef __attribute__((ext_vector_type(4))) float f32x4;

#define OMB  0.2f
#define BETA 0.8f

// ---------------------------------------------------------------------------
// Kernel 1: layer-0 lookup table. table0[v][h] = 0.2*((emb[v]@W_in.T+b_in)@W_lif0.T+b_lif0)
__global__ void k_table(const float* __restrict__ emb, const float* __restrict__ W_in,
                        const float* __restrict__ b_in, const float* __restrict__ W_lif0,
                        const float* __restrict__ b_lif0, float* __restrict__ table0p) {
  __shared__ float x1s[H_SZ];
  int v = blockIdx.x, h = threadIdx.x;
  float s = b_in[h];
  const float* er = emb + v * E_SZ;
  const float* wr = W_in + h * E_SZ;
#pragma unroll 8
  for (int e = 0; e < E_SZ; ++e) s += er[e] * wr[e];
  x1s[h] = s;
  __syncthreads();
  float t0 = b_lif0[h];
  const float* w0 = W_lif0 + h * H_SZ;
#pragma unroll 8
  for (int i = 0; i < H_SZ; ++i) t0 += x1s[i] * w0[i];
  table0p[v * H_SZ + h] = OMB * t0;
}

// ---------------------------------------------------------------------------
// Kernel 2: fused layer0 + layer1 + logits. 128 blocks x 512 threads (8 waves).
// Block = batches [BT*16, BT*16+16), all 128 output neurons (wave w -> n slice).
__launch_bounds__(512, 2)
__global__ void k_fused(const int* __restrict__ ids, const float* __restrict__ table0p,
                        const float* __restrict__ W1, const float* __restrict__ b_lif,
                        const float* __restrict__ W_cls, const float* __restrict__ b_cls,
                        float* __restrict__ out) {
  __shared__ float tbl[V_SZ * H_SZ];                     // 64 KB
  __shared__ int   ids_s[16 * 260];                      // 16.6 KB (4 pad cols)
  __shared__ __align__(16) signed char sb[3][16 * 144];  // 6.9 KB spike tiles

  const int tid = threadIdx.x;
  const int BT  = blockIdx.x;

  // ---- stage table + ids ----
  {
    float4* t4 = (float4*)tbl;
    const float4* g4 = (const float4*)table0p;
#pragma unroll
    for (int i = 0; i < 8; ++i) t4[tid + i * 512] = g4[tid + i * 512];
    const int* gi = ids + BT * 16 * T_STEPS;
#pragma unroll
    for (int i = 0; i < 8; ++i) {
      int idx = tid + i * 512;
      ids_s[(idx >> 8) * 260 + (idx & 255)] = gi[idx];
    }
    if (tid < 64) ids_s[(tid >> 2) * 260 + 256 + (tid & 3)] = 0;  // t=256..259 guard
  }

  // ---- per-lane layer-1 weight fragments (2-plane i8 of 0.2*W_lif1[n,:]) ----
  const int lane = tid & 63, nl = lane & 15, quad = lane >> 4;
  const int n = (tid >> 6) * 16 + nl;                 // output neuron
  const float* wrow = W1 + n * H_SZ;
  float mx = 1e-20f;
  {
    const float4* w4 = (const float4*)wrow;
#pragma unroll
    for (int i = 0; i < 32; ++i) {
      float4 x = w4[i];
      mx = fmaxf(mx, fmaxf(fmaxf(fabsf(x.x), fabsf(x.y)), fmaxf(fabsf(x.z), fabsf(x.w))));
    }
  }
  mx *= OMB;
  float S1 = 126.0f / mx, inv1 = 1.0f / S1;
  float S2 = S1 * 252.0f, inv2 = 1.0f / S2;
  i32x4 Wq1[2], Wq2[2];
#pragma unroll
  for (int kt = 0; kt < 2; ++kt) {
    int q1w[4] = {0, 0, 0, 0}, q2w[4] = {0, 0, 0, 0};
#pragma unroll
    for (int jj = 0; jj < 16; ++jj) {
      int k = kt * 64 + quad * 16 + jj;
      float ww = OMB * wrow[k];
      float q1 = rintf(ww * S1);
      float r  = fmaf(-q1, inv1, ww);
      float q2 = rintf(r * S2);
      q1w[jj >> 2] |= ((int)q1 & 0xFF) << ((jj & 3) * 8);
      q2w[jj >> 2] |= ((int)q2 & 0xFF) << ((jj & 3) * 8);
    }
    Wq1[kt] = (i32x4){q1w[0], q1w[1], q1w[2], q1w[3]};
    Wq2[kt] = (i32x4){q2w[0], q2w[1], q2w[2], q2w[3]};
  }
  const float b1v = OMB * b_lif[H_SZ + n];

  // ---- phase-A chain assignment: thread -> (batch ab, h0..h0+3) ----
  const int ab = tid >> 5, h0 = (tid & 31) * 4;
  signed char* const myw0 = &sb[0][ab * 144 + h0];
  const int sbstride = 16 * 144;
  const int idrow = ab * 260;

  __syncthreads();

  // ---- prologue: A(0), A(1); prime tv/id pipeline ----
  int id0 = ids_s[idrow + 0], id1 = ids_s[idrow + 1];
  int id2 = ids_s[idrow + 2], idn = ids_s[idrow + 3];
  float4 tv0 = *(const float4*)&tbl[id0 * H_SZ + h0];
  float4 tv1 = *(const float4*)&tbl[id1 * H_SZ + h0];
  float4 tvn = *(const float4*)&tbl[id2 * H_SZ + h0];
  float v0[4] = {0.f, 0.f, 0.f, 0.f};
  {
    unsigned pack = 0;
    v0[0] = tv0.x; pack |= (v0[0] >= 1.f) ? 1u : 0u;        v0[0] = (v0[0] >= 1.f) ? 0.f : v0[0];
    v0[1] = tv0.y; pack |= (v0[1] >= 1.f) ? 0x100u : 0u;    v0[1] = (v0[1] >= 1.f) ? 0.f : v0[1];
    v0[2] = tv0.z; pack |= (v0[2] >= 1.f) ? 0x10000u : 0u;  v0[2] = (v0[2] >= 1.f) ? 0.f : v0[2];
    v0[3] = tv0.w; pack |= (v0[3] >= 1.f) ? 0x1000000u : 0u; v0[3] = (v0[3] >= 1.f) ? 0.f : v0[3];
    *(unsigned*)myw0 = pack;
    pack = 0;
    v0[0] = fmaf(BETA, v0[0], tv1.x); pack |= (v0[0] >= 1.f) ? 1u : 0u;        v0[0] = (v0[0] >= 1.f) ? 0.f : v0[0];
    v0[1] = fmaf(BETA, v0[1], tv1.y); pack |= (v0[1] >= 1.f) ? 0x100u : 0u;    v0[1] = (v0[1] >= 1.f) ? 0.f : v0[1];
    v0[2] = fmaf(BETA, v0[2], tv1.z); pack |= (v0[2] >= 1.f) ? 0x10000u : 0u;  v0[2] = (v0[2] >= 1.f) ? 0.f : v0[2];
    v0[3] = fmaf(BETA, v0[3], tv1.w); pack |= (v0[3] >= 1.f) ? 0x1000000u : 0u; v0[3] = (v0[3] >= 1.f) ? 0.f : v0[3];
    *(unsigned*)(myw0 + sbstride) = pack;
  }
  __syncthreads();

  // ---- B prologue: frags(0) -> Pc; frags(1) -> AFn ----
  const int foff = nl * 144 + quad * 16;   // 144 = 9*16: aligned, worst 2-way bank alias (free)
  const i32x4 Z = {0, 0, 0, 0};
  i32x4 AFc0 = *(const i32x4*)(&sb[0][foff]);
  i32x4 AFc1 = *(const i32x4*)(&sb[0][foff + 64]);
  i32x4 Pc1 = __builtin_amdgcn_mfma_i32_16x16x64_i8(AFc0, Wq1[0], Z, 0, 0, 0);
  Pc1       = __builtin_amdgcn_mfma_i32_16x16x64_i8(AFc1, Wq1[1], Pc1, 0, 0, 0);
  i32x4 Pc2 = __builtin_amdgcn_mfma_i32_16x16x64_i8(AFc0, Wq2[0], Z, 0, 0, 0);
  Pc2       = __builtin_amdgcn_mfma_i32_16x16x64_i8(AFc1, Wq2[1], Pc2, 0, 0, 0);
  i32x4 AFn0 = *(const i32x4*)(&sb[1][foff]);
  i32x4 AFn1 = *(const i32x4*)(&sb[1][foff + 64]);

  f32x4 v1 = {0.f, 0.f, 0.f, 0.f};
  i32x4 cnt = {0, 0, 0, 0};
  int wb = 2;                               // A writes sb[(t+2)%3]

  for (int t = 0; t < T_STEPS; ++t) {
    // A(t+2): v0 advance with tvn, pack spikes, write sb[wb]
    {
      unsigned pack = 0;
      v0[0] = fmaf(BETA, v0[0], tvn.x); pack |= (v0[0] >= 1.f) ? 1u : 0u;        v0[0] = (v0[0] >= 1.f) ? 0.f : v0[0];
      v0[1] = fmaf(BETA, v0[1], tvn.y); pack |= (v0[1] >= 1.f) ? 0x100u : 0u;    v0[1] = (v0[1] >= 1.f) ? 0.f : v0[1];
      v0[2] = fmaf(BETA, v0[2], tvn.z); pack |= (v0[2] >= 1.f) ? 0x10000u : 0u;  v0[2] = (v0[2] >= 1.f) ? 0.f : v0[2];
      v0[3] = fmaf(BETA, v0[3], tvn.w); pack |= (v0[3] >= 1.f) ? 0x1000000u : 0u; v0[3] = (v0[3] >= 1.f) ? 0.f : v0[3];
      *(unsigned*)(myw0 + wb * sbstride) = pack;
    }
    // prefetch tv(t+3), id(t+4)  (pad-guarded; overrun values harmless)
    tvn = *(const float4*)&tbl[idn * H_SZ + h0];
    idn = ids_s[idrow + t + 4];
    // MFMA for step t+1 from AFn
    i32x4 Pn1 = __builtin_amdgcn_mfma_i32_16x16x64_i8(AFn0, Wq1[0], Z, 0, 0, 0);
    Pn1       = __builtin_amdgcn_mfma_i32_16x16x64_i8(AFn1, Wq1[1], Pn1, 0, 0, 0);
    i32x4 Pn2 = __builtin_amdgcn_mfma_i32_16x16x64_i8(AFn0, Wq2[0], Z, 0, 0, 0);
    Pn2       = __builtin_amdgcn_mfma_i32_16x16x64_i8(AFn1, Wq2[1], Pn2, 0, 0, 0);
    // epilogue(t) with Pc
#pragma unroll
    for (int r = 0; r < 4; ++r) {
      int   P   = Pc1[r] * 252 + Pc2[r];           // exact, |P| < 2^23
      float cur = fmaf((float)P, inv2, b1v);
      float nv  = fmaf(BETA, v1[r], cur);
      bool  sp  = nv >= 1.0f;
      cnt[r] += sp ? 1 : 0;
      v1[r]   = sp ? 0.0f : nv;
    }
    __syncthreads();
    // reload AFn = frags(t+2) just written to sb[wb]
    Pc1 = Pn1; Pc2 = Pn2;
    AFn0 = *(const i32x4*)(&sb[wb][foff]);
    AFn1 = *(const i32x4*)(&sb[wb][foff + 64]);
    wb = (wb == 2) ? 0 : wb + 1;
  }

  // ---- in-block logits: reuse tbl LDS as cnt buffer [16 x 128] ----
  __syncthreads();
  float* cnt_s = tbl;
#pragma unroll
  for (int r = 0; r < 4; ++r) cnt_s[(quad * 4 + r) * H_SZ + n] = (float)cnt[r];
  __syncthreads();
  if (tid < 16 * C_SZ) {
    int lb = tid / C_SZ, c = tid - lb * C_SZ;
    const float4* cr = (const float4*)(cnt_s + lb * H_SZ);
    const float4* wr = (const float4*)(W_cls + c * H_SZ);
    float s = 0.0f;
#pragma unroll
    for (int i = 0; i < 32; ++i) {
      float4 a = cr[i], w = wr[i];
      s += a.x * w.x + a.y * w.y + a.z * w.z + a.w * w.w;
    }
    out[(BT * 16 + lb) * C_SZ + c] = fmaf(s, 0.00390625f, b_cls[c]);
  }
}

// ---------------------------------------------------------------------------
extern "C" void kernel_launch(void* const* d_in, const int* in_sizes, int n_in,
                              void* d_out, int out_size, void* d_ws, size_t ws_size,
                              hipStream_t stream) {
  (void)in_sizes; (void)n_in; (void)out_size; (void)ws_size;
  const int*   ids   = (const int*)d_in[0];
  const float* emb   = (const float*)d_in[1];
  const float* W_in  = (const float*)d_in[2];
  const float* b_in  = (const float*)d_in[3];
  const float* W_lif = (const float*)d_in[4];
  const float* b_lif = (const float*)d_in[5];
  // d_in[6] (W_rec) provably unused in forward
  const float* W_cls = (const float*)d_in[7];
  const float* b_cls = (const float*)d_in[8];
  float* out = (float*)d_out;

  float* table0p = (float*)d_ws;   // 64 KB scratch

  k_table<<<V_SZ, H_SZ, 0, stream>>>(emb, W_in, b_in, W_lif, b_lif, table0p);
  k_fused<<<128, 512, 0, stream>>>(ids, table0p, W_lif + H_SZ * H_SZ, b_lif,
                                   W_cls, b_cls, out);
}

// Round 5
// 145.309 us; speedup vs baseline: 1.0895x; 1.0895x over previous
//
#include <hip/hip_runtime.h>

// RuleClassifierSNN — forward only, fully fused, group-pipelined.
//  * spike(post-reset v) == 0 always -> W_rec vanishes in forward.
//  * layer-0 drive is a V=128-entry lookup table (0.2f-folded) -> LDS.
//  * layer-1 GEMM: spikes {0,1} as i8 in LDS; W as 2-plane i8 fixed point
//    (q1 + q2/252, per-row scale); exact i32 accumulate, P=252*P1+P2 exact.
//  * 256 blocks x 256 thr: 8 batches/block (all CUs). G=8 steps per barrier,
//    double-buffered spike tiles; MFMA rows 8..15 = duplicates of 0..7
//    (nl&7 addressing, broadcast = free), epilogue results taken from quads 0-1.

#define T_STEPS 256
#define B_SZ    2048
#define H_SZ    128
#define V_SZ    128
#define E_SZ    64
#define C_SZ    12

typedef __attribute__((ext_vector_type(4))) int   i32x4;
typedef __attribute__((ext_vector_type(4))) float f32x4;

#define OMB  0.2f
#define BETA 0.8f

#define GSTEP   8
#define SBSTRIDE 144           // 8 rows used; 144B row pitch (16B aligned)
#define SBGROUP (GSTEP * 1152) // 1152 = 8*144 per step

// ---------------------------------------------------------------------------
// Kernel 1: layer-0 lookup table. table0[v][h] = 0.2*((emb[v]@W_in.T+b_in)@W_lif0.T+b_lif0)
__global__ void k_table(const float* __restrict__ emb, const float* __restrict__ W_in,
                        const float* __restrict__ b_in, const float* __restrict__ W_lif0,
                        const float* __restrict__ b_lif0, float* __restrict__ table0p) {
  __shared__ float x1s[H_SZ];
  int v = blockIdx.x, h = threadIdx.x;
  float s = b_in[h];
  const float* er = emb + v * E_SZ;
  const float* wr = W_in + h * E_SZ;
#pragma unroll 8
  for (int e = 0; e < E_SZ; ++e) s += er[e] * wr[e];
  x1s[h] = s;
  __syncthreads();
  float t0 = b_lif0[h];
  const float* w0 = W_lif0 + h * H_SZ;
#pragma unroll 8
  for (int i = 0; i < H_SZ; ++i) t0 += x1s[i] * w0[i];
  table0p[v * H_SZ + h] = OMB * t0;
}

// ---------------------------------------------------------------------------
// Kernel 2: fused layer0 + layer1 + logits.
__launch_bounds__(256, 1)
__global__ void k_fused(const int* __restrict__ ids, const float* __restrict__ table0p,
                        const float* __restrict__ W1, const float* __restrict__ b_lif,
                        const float* __restrict__ W_cls, const float* __restrict__ b_cls,
                        float* __restrict__ out) {
  __shared__ float tbl[V_SZ * H_SZ];                       // 64 KB
  __shared__ int   ids_s[8 * 264];                         // 8.25 KB (stride stagger)
  __shared__ __align__(16) signed char sb[2][SBGROUP];     // 18 KB spike tiles

  const int tid = threadIdx.x;
  const int BT  = blockIdx.x;                              // batches [BT*8, BT*8+8)

  // ---- stage table + ids ----
  {
    float4* t4 = (float4*)tbl;
    const float4* g4 = (const float4*)table0p;
#pragma unroll
    for (int i = 0; i < 16; ++i) t4[tid + i * 256] = g4[tid + i * 256];
    const int* gi = ids + BT * 8 * T_STEPS;
#pragma unroll
    for (int i = 0; i < 8; ++i) {
      int idx = tid + i * 256;
      ids_s[(idx >> 8) * 264 + (idx & 255)] = gi[idx];
    }
  }

  // ---- B setup: per-lane 2-plane i8 weights for TWO n-tiles ----
  const int lane = tid & 63, nl = lane & 15, quad = lane >> 4;
  const int w = tid >> 6;                                  // wave 0..3
  const int nA = w * 16 + nl, nB = 64 + w * 16 + nl;
  i32x4 Wq1[2][2], Wq2[2][2];                              // [ntile][kt]
  float inv2v[2], b1vv[2];
#pragma unroll
  for (int nt = 0; nt < 2; ++nt) {
    const int n = nt ? nB : nA;
    const float* wrow = W1 + n * H_SZ;
    const float4* w4 = (const float4*)wrow;
    float mx = 1e-20f;
#pragma unroll
    for (int i = 0; i < 32; ++i) {
      float4 x = w4[i];
      mx = fmaxf(mx, fmaxf(fmaxf(fabsf(x.x), fabsf(x.y)), fmaxf(fabsf(x.z), fabsf(x.w))));
    }
    mx *= OMB;
    float S1 = 126.0f / mx, inv1 = 1.0f / S1;
    float S2 = S1 * 252.0f;
    inv2v[nt] = 1.0f / S2;
#pragma unroll
    for (int kt = 0; kt < 2; ++kt) {
      int q1w[4] = {0, 0, 0, 0}, q2w[4] = {0, 0, 0, 0};
#pragma unroll
      for (int jj = 0; jj < 16; ++jj) {
        int k = kt * 64 + quad * 16 + jj;
        float ww = OMB * wrow[k];
        float q1 = rintf(ww * S1);
        float r  = fmaf(-q1, inv1, ww);
        float q2 = rintf(r * S2);
        q1w[jj >> 2] |= ((int)q1 & 0xFF) << ((jj & 3) * 8);
        q2w[jj >> 2] |= ((int)q2 & 0xFF) << ((jj & 3) * 8);
      }
      Wq1[nt][kt] = (i32x4){q1w[0], q1w[1], q1w[2], q1w[3]};
      Wq2[nt][kt] = (i32x4){q2w[0], q2w[1], q2w[2], q2w[3]};
    }
    b1vv[nt] = OMB * b_lif[H_SZ + n];
  }

  // ---- A mapping: thread -> (batch ab, h0..h0+3) ----
  const int ab = tid >> 5, h0 = (tid & 31) * 4;
  const int* idrow = &ids_s[ab * 264];
  signed char* const wbase = &sb[0][0] + ab * SBSTRIDE + h0;
  // B frag base (rows 8..15 duplicate 0..7 -> 2-way broadcast, free)
  const int fo = (nl & 7) * SBSTRIDE + quad * 16;

  __syncthreads();

  float v0[4] = {0.f, 0.f, 0.f, 0.f};

  // A-phase for one group of 8 steps -> buffer `buf`
  auto a_group = [&](int gg, int buf) {
    const int tb = gg * GSTEP;
    float4 tv[GSTEP];
#pragma unroll
    for (int s = 0; s < GSTEP; ++s)
      tv[s] = *(const float4*)&tbl[idrow[tb + s] * H_SZ + h0];
    signed char* bp = wbase + buf * SBGROUP;
#pragma unroll
    for (int s = 0; s < GSTEP; ++s) {
      unsigned pack = 0;
      float nv;
      nv = fmaf(BETA, v0[0], tv[s].x); pack |= (nv >= 1.f) ? 0x01u : 0u;       v0[0] = (nv >= 1.f) ? 0.f : nv;
      nv = fmaf(BETA, v0[1], tv[s].y); pack |= (nv >= 1.f) ? 0x0100u : 0u;     v0[1] = (nv >= 1.f) ? 0.f : nv;
      nv = fmaf(BETA, v0[2], tv[s].z); pack |= (nv >= 1.f) ? 0x010000u : 0u;   v0[2] = (nv >= 1.f) ? 0.f : nv;
      nv = fmaf(BETA, v0[3], tv[s].w); pack |= (nv >= 1.f) ? 0x01000000u : 0u; v0[3] = (nv >= 1.f) ? 0.f : nv;
      *(unsigned*)(bp + s * 1152) = pack;
    }
  };

  a_group(0, 0);
  __syncthreads();

  f32x4 v1[2] = {{0.f, 0.f, 0.f, 0.f}, {0.f, 0.f, 0.f, 0.f}};
  i32x4 cnt[2] = {{0, 0, 0, 0}, {0, 0, 0, 0}};
  const i32x4 Z = {0, 0, 0, 0};

  for (int g = 0; g < T_STEPS / GSTEP; ++g) {
    const int p = g & 1;
    const signed char* rp = &sb[p][0] + fo;
    // issue all frag loads for this group up-front
    i32x4 AF[GSTEP][2];
#pragma unroll
    for (int s = 0; s < GSTEP; ++s) {
      AF[s][0] = *(const i32x4*)(rp + s * 1152);
      AF[s][1] = *(const i32x4*)(rp + s * 1152 + 64);
    }
    // A produces next group into the other buffer
    if (g < T_STEPS / GSTEP - 1) a_group(g + 1, p ^ 1);

    // B: MFMAs one step ahead of the serial v1 epilogue
    i32x4 Pc1[2], Pc2[2];
#pragma unroll
    for (int nt = 0; nt < 2; ++nt) {
      Pc1[nt] = __builtin_amdgcn_mfma_i32_16x16x64_i8(AF[0][0], Wq1[nt][0], Z, 0, 0, 0);
      Pc1[nt] = __builtin_amdgcn_mfma_i32_16x16x64_i8(AF[0][1], Wq1[nt][1], Pc1[nt], 0, 0, 0);
      Pc2[nt] = __builtin_amdgcn_mfma_i32_16x16x64_i8(AF[0][0], Wq2[nt][0], Z, 0, 0, 0);
      Pc2[nt] = __builtin_amdgcn_mfma_i32_16x16x64_i8(AF[0][1], Wq2[nt][1], Pc2[nt], 0, 0, 0);
    }
#pragma unroll
    for (int s = 0; s < GSTEP; ++s) {
      i32x4 Pn1[2], Pn2[2];
      if (s < GSTEP - 1) {
#pragma unroll
        for (int nt = 0; nt < 2; ++nt) {
          Pn1[nt] = __builtin_amdgcn_mfma_i32_16x16x64_i8(AF[s + 1][0], Wq1[nt][0], Z, 0, 0, 0);
          Pn1[nt] = __builtin_amdgcn_mfma_i32_16x16x64_i8(AF[s + 1][1], Wq1[nt][1], Pn1[nt], 0, 0, 0);
          Pn2[nt] = __builtin_amdgcn_mfma_i32_16x16x64_i8(AF[s + 1][0], Wq2[nt][0], Z, 0, 0, 0);
          Pn2[nt] = __builtin_amdgcn_mfma_i32_16x16x64_i8(AF[s + 1][1], Wq2[nt][1], Pn2[nt], 0, 0, 0);
        }
      }
#pragma unroll
      for (int nt = 0; nt < 2; ++nt) {
#pragma unroll
        for (int r = 0; r < 4; ++r) {
          int   P   = Pc1[nt][r] * 252 + Pc2[nt][r];       // exact, |P| < 2^23
          float cur = fmaf((float)P, inv2v[nt], b1vv[nt]);
          float nv  = fmaf(BETA, v1[nt][r], cur);
          bool  sp  = nv >= 1.0f;
          cnt[nt][r] += sp ? 1 : 0;
          v1[nt][r]   = sp ? 0.0f : nv;
        }
        if (s < GSTEP - 1) { Pc1[nt] = Pn1[nt]; Pc2[nt] = Pn2[nt]; }
      }
    }
    __syncthreads();
  }

  // ---- in-block logits: reuse tbl LDS as cnt buffer [8 x 128] ----
  float* cnt_s = tbl;
  if (quad < 2) {
#pragma unroll
    for (int r = 0; r < 4; ++r) {
      int bl = quad * 4 + r;
      cnt_s[bl * H_SZ + nA] = (float)cnt[0][r];
      cnt_s[bl * H_SZ + nB] = (float)cnt[1][r];
    }
  }
  __syncthreads();
  if (tid < 8 * C_SZ) {
    int lb = tid / C_SZ, c = tid - lb * C_SZ;
    const float4* cr = (const float4*)(cnt_s + lb * H_SZ);
    const float4* wr = (const float4*)(W_cls + c * H_SZ);
    float s = 0.0f;
#pragma unroll
    for (int i = 0; i < 32; ++i) {
      float4 a = cr[i], ww = wr[i];
      s += a.x * ww.x + a.y * ww.y + a.z * ww.z + a.w * ww.w;
    }
    out[(BT * 8 + lb) * C_SZ + c] = fmaf(s, 0.00390625f, b_cls[c]);
  }
}

// ---------------------------------------------------------------------------
extern "C" void kernel_launch(void* const* d_in, const int* in_sizes, int n_in,
                              void* d_out, int out_size, void* d_ws, size_t ws_size,
                              hipStream_t stream) {
  (void)in_sizes; (void)n_in; (void)out_size; (void)ws_size;
  const int*   ids   = (const int*)d_in[0];
  const float* emb   = (const float*)d_in[1];
  const float* W_in  = (const float*)d_in[2];
  const float* b_in  = (const float*)d_in[3];
  const float* W_lif = (const float*)d_in[4];
  const float* b_lif = (const float*)d_in[5];
  // d_in[6] (W_rec) provably unused in forward
  const float* W_cls = (const float*)d_in[7];
  const float* b_cls = (const float*)d_in[8];
  float* out = (float*)d_out;

  float* table0p = (float*)d_ws;   // 64 KB scratch

  k_table<<<V_SZ, H_SZ, 0, stream>>>(emb, W_in, b_in, W_lif, b_lif, table0p);
  k_fused<<<256, 256, 0, stream>>>(ids, table0p, W_lif + H_SZ * H_SZ, b_lif,
                                   W_cls, b_cls, out);
}

// Round 6
// 139.717 us; speedup vs baseline: 1.1331x; 1.0400x over previous
//
#include <hip/hip_runtime.h>

// RuleClassifierSNN — forward only, fully fused, 8-wave (2/SIMD) pipeline.
//  * spike(post-reset v) == 0 always -> W_rec vanishes in forward.
//  * layer-0 drive is a V=128-entry lookup table (0.2f-folded) -> LDS (row pad 132).
//  * layer-1 GEMM: spikes {0,1} as i8 in LDS; W as 2-plane i8 fixed point
//    (q1 + q2/252, per-row scale); exact i32 accumulate, P=252*P1+P2 exact.
//  * 256 blocks x 512 thr: 8 batches/block; wave w = A-chain of batch w +
//    B-tile of 16 n. G=8 steps/barrier, double-buffered spike tiles.

#define T_STEPS 256
#define B_SZ    2048
#define H_SZ    128
#define V_SZ    128
#define E_SZ    64
#define C_SZ    12

typedef __attribute__((ext_vector_type(4))) int   i32x4;
typedef __attribute__((ext_vector_type(4))) float f32x4;

#define OMB  0.2f
#define BETA 0.8f

#define GSTEP    8
#define TPITCH   132            // table row pitch in floats (bank stagger)
#define SBSTRIDE 144            // spike row pitch bytes (16B aligned)
#define SBSTEP   1152           // 8 rows * 144
#define SBGROUP  (GSTEP * SBSTEP)

// ---------------------------------------------------------------------------
// Kernel 1: layer-0 lookup table. table0[v][h] = 0.2*((emb[v]@W_in.T+b_in)@W_lif0.T+b_lif0)
__global__ void k_table(const float* __restrict__ emb, const float* __restrict__ W_in,
                        const float* __restrict__ b_in, const float* __restrict__ W_lif0,
                        const float* __restrict__ b_lif0, float* __restrict__ table0p) {
  __shared__ float x1s[H_SZ];
  int v = blockIdx.x, h = threadIdx.x;
  float s = b_in[h];
  const float* er = emb + v * E_SZ;
  const float* wr = W_in + h * E_SZ;
#pragma unroll 8
  for (int e = 0; e < E_SZ; ++e) s += er[e] * wr[e];
  x1s[h] = s;
  __syncthreads();
  float t0 = b_lif0[h];
  const float* w0 = W_lif0 + h * H_SZ;
#pragma unroll 8
  for (int i = 0; i < H_SZ; ++i) t0 += x1s[i] * w0[i];
  table0p[v * H_SZ + h] = OMB * t0;
}

// ---------------------------------------------------------------------------
// Kernel 2: fused layer0 + layer1 + logits. 256 blocks x 512 threads (8 waves).
__launch_bounds__(512, 1)
__global__ void k_fused(const int* __restrict__ ids, const float* __restrict__ table0p,
                        const float* __restrict__ W1, const float* __restrict__ b_lif,
                        const float* __restrict__ W_cls, const float* __restrict__ b_cls,
                        float* __restrict__ out) {
  __shared__ float tbl[V_SZ * TPITCH];                     // 67.6 KB (padded rows)
  __shared__ int   ids_s[8 * 264];                         // 8.4 KB
  __shared__ __align__(16) signed char sb[2][SBGROUP];     // 18.4 KB

  const int tid = threadIdx.x;
  const int BT  = blockIdx.x;                              // batches [BT*8, BT*8+8)
  const int lane = tid & 63, w = tid >> 6;                 // wave 0..7
  const int nl = lane & 15, quad = lane >> 4;

  // ---- stage table (with row pad) + ids ----
  {
    const float4* g4 = (const float4*)table0p;
#pragma unroll
    for (int i = 0; i < 8; ++i) {
      int idx4 = tid + i * 512;                 // [0,4096) float4 units
      int v = idx4 >> 5, c = idx4 & 31;
      *(float4*)&tbl[v * TPITCH + c * 4] = g4[idx4];
    }
    const int* gi = ids + BT * 8 * T_STEPS;
#pragma unroll
    for (int i = 0; i < 4; ++i) {
      int idx = tid + i * 512;
      ids_s[(idx >> 8) * 264 + (idx & 255)] = gi[idx];
    }
  }

  // ---- B setup: wave w -> n-tile w. 2-plane i8 weights of 0.2*W_lif1[n,:] ----
  const int n = w * 16 + nl;
  const float* wrow = W1 + n * H_SZ;
  float mx = 1e-20f;
  {
    const float4* w4 = (const float4*)wrow;
#pragma unroll
    for (int i = 0; i < 32; ++i) {
      float4 x = w4[i];
      mx = fmaxf(mx, fmaxf(fmaxf(fabsf(x.x), fabsf(x.y)), fmaxf(fabsf(x.z), fabsf(x.w))));
    }
  }
  mx *= OMB;
  float S1 = 126.0f / mx, inv1 = 1.0f / S1;
  float S2 = S1 * 252.0f, inv2 = 1.0f / S2;
  i32x4 Wq1[2], Wq2[2];
#pragma unroll
  for (int kt = 0; kt < 2; ++kt) {
    int q1w[4] = {0, 0, 0, 0}, q2w[4] = {0, 0, 0, 0};
#pragma unroll
    for (int jj = 0; jj < 16; ++jj) {
      int k = kt * 64 + quad * 16 + jj;
      float ww = OMB * wrow[k];
      float q1 = rintf(ww * S1);
      float r  = fmaf(-q1, inv1, ww);
      float q2 = rintf(r * S2);
      q1w[jj >> 2] |= ((int)q1 & 0xFF) << ((jj & 3) * 8);
      q2w[jj >> 2] |= ((int)q2 & 0xFF) << ((jj & 3) * 8);
    }
    Wq1[kt] = (i32x4){q1w[0], q1w[1], q1w[2], q1w[3]};
    Wq2[kt] = (i32x4){q2w[0], q2w[1], q2w[2], q2w[3]};
  }
  const float b1v = OMB * b_lif[H_SZ + n];

  // ---- A mapping: wave w owns batch w; thread -> h = 2*lane, 2*lane+1 ----
  const int* idrow = &ids_s[w * 264];
  const int tcol = 2 * lane;                               // h base
  signed char* const wbase = &sb[0][0] + w * SBSTRIDE + tcol;
  const int fo = (nl & 7) * SBSTRIDE + quad * 16;          // B frag base

  __syncthreads();

  float v00 = 0.f, v01 = 0.f;

  auto a_group = [&](int gg, int buf) {
    const int tb = gg * GSTEP;
    int   idv[GSTEP];
#pragma unroll
    for (int s = 0; s < GSTEP; ++s) idv[s] = idrow[tb + s];   // LDS broadcast
    float2 tv[GSTEP];
#pragma unroll
    for (int s = 0; s < GSTEP; ++s)
      tv[s] = *(const float2*)&tbl[idv[s] * TPITCH + tcol];
    signed char* bp = wbase + buf * SBGROUP;
#pragma unroll
    for (int s = 0; s < GSTEP; ++s) {
      float nv0 = fmaf(BETA, v00, tv[s].x);
      float nv1 = fmaf(BETA, v01, tv[s].y);
      bool sp0 = nv0 >= 1.f, sp1 = nv1 >= 1.f;
      v00 = sp0 ? 0.f : nv0;
      v01 = sp1 ? 0.f : nv1;
      unsigned short pack = (unsigned short)((sp0 ? 1u : 0u) | (sp1 ? 0x100u : 0u));
      *(unsigned short*)(bp + s * SBSTEP) = pack;
    }
  };

  a_group(0, 0);
  __syncthreads();

  f32x4 v1 = {0.f, 0.f, 0.f, 0.f};
  int cnt[4] = {0, 0, 0, 0};
  const i32x4 Z = {0, 0, 0, 0};

  for (int g = 0; g < T_STEPS / GSTEP; ++g) {
    const int p = g & 1;
    const signed char* rp = &sb[p][0] + fo;
    i32x4 AF[GSTEP][2];
#pragma unroll
    for (int s = 0; s < GSTEP; ++s) {
      AF[s][0] = *(const i32x4*)(rp + s * SBSTEP);
      AF[s][1] = *(const i32x4*)(rp + s * SBSTEP + 64);
    }
    if (g < T_STEPS / GSTEP - 1) a_group(g + 1, p ^ 1);

    // MFMA one step ahead of the serial v1 epilogue
    i32x4 Pc1 = __builtin_amdgcn_mfma_i32_16x16x64_i8(AF[0][0], Wq1[0], Z, 0, 0, 0);
    Pc1       = __builtin_amdgcn_mfma_i32_16x16x64_i8(AF[0][1], Wq1[1], Pc1, 0, 0, 0);
    i32x4 Pc2 = __builtin_amdgcn_mfma_i32_16x16x64_i8(AF[0][0], Wq2[0], Z, 0, 0, 0);
    Pc2       = __builtin_amdgcn_mfma_i32_16x16x64_i8(AF[0][1], Wq2[1], Pc2, 0, 0, 0);
#pragma unroll
    for (int s = 0; s < GSTEP; ++s) {
      i32x4 Pn1, Pn2;
      if (s < GSTEP - 1) {
        Pn1 = __builtin_amdgcn_mfma_i32_16x16x64_i8(AF[s + 1][0], Wq1[0], Z, 0, 0, 0);
        Pn1 = __builtin_amdgcn_mfma_i32_16x16x64_i8(AF[s + 1][1], Wq1[1], Pn1, 0, 0, 0);
        Pn2 = __builtin_amdgcn_mfma_i32_16x16x64_i8(AF[s + 1][0], Wq2[0], Z, 0, 0, 0);
        Pn2 = __builtin_amdgcn_mfma_i32_16x16x64_i8(AF[s + 1][1], Wq2[1], Pn2, 0, 0, 0);
      }
#pragma unroll
      for (int r = 0; r < 4; ++r) {
        int   P   = Pc1[r] * 252 + Pc2[r];         // exact, |P| < 2^23
        float cur = fmaf((float)P, inv2, b1v);
        float nv  = fmaf(BETA, v1[r], cur);
        bool  sp  = nv >= 1.0f;
        cnt[r] += sp ? 1 : 0;
        v1[r]  = sp ? 0.0f : nv;
      }
      if (s < GSTEP - 1) { Pc1 = Pn1; Pc2 = Pn2; }
    }
    __syncthreads();
  }

  // ---- in-block logits: reuse ids_s LDS as cnt buffer [8 x 128] ----
  float* cnt_s = (float*)ids_s;
  if (quad < 2) {
#pragma unroll
    for (int r = 0; r < 4; ++r)
      cnt_s[(quad * 4 + r) * H_SZ + n] = (float)cnt[r];
  }
  __syncthreads();
  if (tid < 8 * C_SZ) {
    int lb = tid / C_SZ, c = tid - lb * C_SZ;
    const float4* cr = (const float4*)(cnt_s + lb * H_SZ);
    const float4* wr = (const float4*)(W_cls + c * H_SZ);
    float s = 0.0f;
#pragma unroll
    for (int i = 0; i < 32; ++i) {
      float4 a = cr[i], ww = wr[i];
      s += a.x * ww.x + a.y * ww.y + a.z * ww.z + a.w * ww.w;
    }
    out[(BT * 8 + lb) * C_SZ + c] = fmaf(s, 0.00390625f, b_cls[c]);
  }
}

// ---------------------------------------------------------------------------
extern "C" void kernel_launch(void* const* d_in, const int* in_sizes, int n_in,
                              void* d_out, int out_size, void* d_ws, size_t ws_size,
                              hipStream_t stream) {
  (void)in_sizes; (void)n_in; (void)out_size; (void)ws_size;
  const int*   ids   = (const int*)d_in[0];
  const float* emb   = (const float*)d_in[1];
  const float* W_in  = (const float*)d_in[2];
  const float* b_in  = (const float*)d_in[3];
  const float* W_lif = (const float*)d_in[4];
  const float* b_lif = (const float*)d_in[5];
  // d_in[6] (W_rec) provably unused in forward
  const float* W_cls = (const float*)d_in[7];
  const float* b_cls = (const float*)d_in[8];
  float* out = (float*)d_out;

  float* table0p = (float*)d_ws;   // 64 KB scratch

  k_table<<<V_SZ, H_SZ, 0, stream>>>(emb, W_in, b_in, W_lif, b_lif, table0p);
  k_fused<<<256, 512, 0, stream>>>(ids, table0p, W_lif + H_SZ * H_SZ, b_lif,
                                   W_cls, b_cls, out);
}

// Round 7
// 126.418 us; speedup vs baseline: 1.2523x; 1.1052x over previous
//
#include <hip/hip_runtime.h>

// RuleClassifierSNN — forward only, fused, wave-specialized producer/consumer.
//  * spike(post-reset v) == 0 always -> W_rec vanishes in forward.
//  * layer-0 drive is a V=128-entry lookup table (0.2f-folded) -> LDS.
//  * layer-1 GEMM: spikes {0,1} as i8 in LDS; W as 2-plane i8 fixed point
//    (q1 + q2/252, per-row scale); exact i32 accumulate, P=252*P1+P2 exact.
//  * 256 blocks x 512 thr. Block = 16 batches x 64 n (n-half by blockIdx&1).
//    Waves 0-3: layer-0 chains (8 h per thread, ILP 8). Waves 4-7: one 16-n
//    MFMA tile each, all 16 M-rows useful. G=8 steps/barrier, double buffer.

#define T_STEPS 256
#define B_SZ    2048
#define H_SZ    128
#define V_SZ    128
#define E_SZ    64
#define C_SZ    12

typedef __attribute__((ext_vector_type(4))) int   i32x4;
typedef __attribute__((ext_vector_type(4))) float f32x4;

#define OMB  0.2f
#define BETA 0.8f

#define GSTEP  8
#define ROWP   144                  // spike row pitch (bytes)
#define STEPP  (16 * ROWP)          // 2304 B per step tile
#define GROUPP (GSTEP * STEPP)      // 18432 B per group buffer
#define IDP    260                  // ids row pitch (ints, bank stagger)

// ---------------------------------------------------------------------------
// Kernel 1: layer-0 lookup table. table0[v][h] = 0.2*((emb[v]@W_in.T+b_in)@W_lif0.T+b_lif0)
__global__ void k_table(const float* __restrict__ emb, const float* __restrict__ W_in,
                        const float* __restrict__ b_in, const float* __restrict__ W_lif0,
                        const float* __restrict__ b_lif0, float* __restrict__ table0p) {
  __shared__ float x1s[H_SZ];
  int v = blockIdx.x, h = threadIdx.x;
  float s = b_in[h];
  const float* er = emb + v * E_SZ;
  const float* wr = W_in + h * E_SZ;
#pragma unroll 8
  for (int e = 0; e < E_SZ; ++e) s += er[e] * wr[e];
  x1s[h] = s;
  __syncthreads();
  float t0 = b_lif0[h];
  const float* w0 = W_lif0 + h * H_SZ;
#pragma unroll 8
  for (int i = 0; i < H_SZ; ++i) t0 += x1s[i] * w0[i];
  table0p[v * H_SZ + h] = OMB * t0;
}

// ---------------------------------------------------------------------------
// Kernel 2: fused layer0 + layer1 + partial logits.
__launch_bounds__(512, 1)
__global__ void k_fused(const int* __restrict__ ids, const float* __restrict__ table0p,
                        const float* __restrict__ W1, const float* __restrict__ b_lif,
                        const float* __restrict__ W_cls, float* __restrict__ part) {
  __shared__ float tbl[V_SZ * H_SZ];                     // 64 KB
  __shared__ int   ids_s[16 * IDP];                      // 16.6 KB
  __shared__ __align__(16) signed char sb[2][GROUPP];    // 36.9 KB

  const int tid = threadIdx.x;
  const int BG  = blockIdx.x >> 1;      // batch group: batches [BG*16, BG*16+16)
  const int NH  = blockIdx.x & 1;       // n half: n in [NH*64, NH*64+64)
  const int lane = tid & 63, w = tid >> 6;
  const int nl = lane & 15, quad = lane >> 4;

  // ---- stage table + ids (all 512 threads) ----
  {
    const float4* g4 = (const float4*)table0p;
    float4* t4 = (float4*)tbl;
#pragma unroll
    for (int i = 0; i < 8; ++i) t4[tid + i * 512] = g4[tid + i * 512];
    const int* gi = ids + BG * 16 * T_STEPS;
#pragma unroll
    for (int i = 0; i < 8; ++i) {
      int idx = tid + i * 512;
      ids_s[(idx >> 8) * IDP + (idx & 255)] = gi[idx];
    }
  }

  // ---- A-wave state (waves 0-3): batch = w*4 + (lane>>4), 8 h per thread ----
  const int batch = w * 4 + (lane >> 4);       // valid for w<4
  const int h0 = nl * 4;                       // h0..h0+3 and h0+64..h0+67
  const int* idrow = &ids_s[(batch & 15) * IDP];
  float va[4] = {0.f, 0.f, 0.f, 0.f};
  float vc[4] = {0.f, 0.f, 0.f, 0.f};

  auto a_group = [&](int gg, int buf) {
    const int tb = gg * GSTEP;
    int idv[GSTEP];
#pragma unroll
    for (int s = 0; s < GSTEP; ++s) idv[s] = idrow[tb + s];     // broadcast
    float4 ta[GSTEP], tc[GSTEP];
#pragma unroll
    for (int s = 0; s < GSTEP; ++s) {
      const float* tp = &tbl[idv[s] * H_SZ + h0];
      ta[s] = *(const float4*)tp;
      tc[s] = *(const float4*)(tp + 64);
    }
    signed char* wb = &sb[buf][0] + batch * ROWP + h0;
#pragma unroll
    for (int s = 0; s < GSTEP; ++s) {
      unsigned pa = 0, pb = 0;
      float nv;
      nv = fmaf(BETA, va[0], ta[s].x); pa |= (nv >= 1.f) ? 0x01u : 0u;       va[0] = (nv >= 1.f) ? 0.f : nv;
      nv = fmaf(BETA, va[1], ta[s].y); pa |= (nv >= 1.f) ? 0x0100u : 0u;     va[1] = (nv >= 1.f) ? 0.f : nv;
      nv = fmaf(BETA, va[2], ta[s].z); pa |= (nv >= 1.f) ? 0x010000u : 0u;   va[2] = (nv >= 1.f) ? 0.f : nv;
      nv = fmaf(BETA, va[3], ta[s].w); pa |= (nv >= 1.f) ? 0x01000000u : 0u; va[3] = (nv >= 1.f) ? 0.f : nv;
      nv = fmaf(BETA, vc[0], tc[s].x); pb |= (nv >= 1.f) ? 0x01u : 0u;       vc[0] = (nv >= 1.f) ? 0.f : nv;
      nv = fmaf(BETA, vc[1], tc[s].y); pb |= (nv >= 1.f) ? 0x0100u : 0u;     vc[1] = (nv >= 1.f) ? 0.f : nv;
      nv = fmaf(BETA, vc[2], tc[s].z); pb |= (nv >= 1.f) ? 0x010000u : 0u;   vc[2] = (nv >= 1.f) ? 0.f : nv;
      nv = fmaf(BETA, vc[3], tc[s].w); pb |= (nv >= 1.f) ? 0x01000000u : 0u; vc[3] = (nv >= 1.f) ? 0.f : nv;
      *(unsigned*)(wb + s * STEPP) = pa;
      *(unsigned*)(wb + s * STEPP + 64) = pb;
    }
  };

  // ---- B-wave constants (waves 4-7): n-tile = (w-4), n = NH*64 + tile*16+nl ----
  i32x4 Wq1[2], Wq2[2];
  float inv2 = 0.f, b1v = 0.f;
  const int n = NH * 64 + (w - 4) * 16 + nl;   // valid for w>=4
  if (w >= 4) {
    const float* wrow = W1 + n * H_SZ;
    const float4* w4 = (const float4*)wrow;
    float mx = 1e-20f;
#pragma unroll
    for (int i = 0; i < 32; ++i) {
      float4 x = w4[i];
      mx = fmaxf(mx, fmaxf(fmaxf(fabsf(x.x), fabsf(x.y)), fmaxf(fabsf(x.z), fabsf(x.w))));
    }
    mx *= OMB;
    float S1 = 126.0f / mx, inv1 = 1.0f / S1;
    float S2 = S1 * 252.0f;
    inv2 = 1.0f / S2;
#pragma unroll
    for (int kt = 0; kt < 2; ++kt) {
      int q1w[4] = {0, 0, 0, 0}, q2w[4] = {0, 0, 0, 0};
#pragma unroll
      for (int jj = 0; jj < 16; ++jj) {
        int k = kt * 64 + quad * 16 + jj;
        float ww = OMB * wrow[k];
        float q1 = rintf(ww * S1);
        float r  = fmaf(-q1, inv1, ww);
        float q2 = rintf(r * S2);
        q1w[jj >> 2] |= ((int)q1 & 0xFF) << ((jj & 3) * 8);
        q2w[jj >> 2] |= ((int)q2 & 0xFF) << ((jj & 3) * 8);
      }
      Wq1[kt] = (i32x4){q1w[0], q1w[1], q1w[2], q1w[3]};
      Wq2[kt] = (i32x4){q2w[0], q2w[1], q2w[2], q2w[3]};
    }
    b1v = OMB * b_lif[H_SZ + n];
  }

  f32x4 v1 = {0.f, 0.f, 0.f, 0.f};
  int cnt[4] = {0, 0, 0, 0};
  const i32x4 Z = {0, 0, 0, 0};
  const signed char* const rbase = &sb[0][0] + nl * ROWP + quad * 16;

  __syncthreads();
  if (w < 4) a_group(0, 0);
  __syncthreads();

  for (int g = 0; g < T_STEPS / GSTEP; ++g) {
    if (w < 4) {
      if (g < T_STEPS / GSTEP - 1) a_group(g + 1, (g + 1) & 1);
    } else {
      const signed char* rp = rbase + (g & 1) * GROUPP;
      i32x4 AF0[GSTEP], AF1[GSTEP];
#pragma unroll
      for (int s = 0; s < GSTEP; ++s) {
        AF0[s] = *(const i32x4*)(rp + s * STEPP);
        AF1[s] = *(const i32x4*)(rp + s * STEPP + 64);
      }
      i32x4 Pc1 = __builtin_amdgcn_mfma_i32_16x16x64_i8(AF0[0], Wq1[0], Z, 0, 0, 0);
      Pc1       = __builtin_amdgcn_mfma_i32_16x16x64_i8(AF1[0], Wq1[1], Pc1, 0, 0, 0);
      i32x4 Pc2 = __builtin_amdgcn_mfma_i32_16x16x64_i8(AF0[0], Wq2[0], Z, 0, 0, 0);
      Pc2       = __builtin_amdgcn_mfma_i32_16x16x64_i8(AF1[0], Wq2[1], Pc2, 0, 0, 0);
#pragma unroll
      for (int s = 0; s < GSTEP; ++s) {
        i32x4 Pn1, Pn2;
        if (s < GSTEP - 1) {
          Pn1 = __builtin_amdgcn_mfma_i32_16x16x64_i8(AF0[s + 1], Wq1[0], Z, 0, 0, 0);
          Pn1 = __builtin_amdgcn_mfma_i32_16x16x64_i8(AF1[s + 1], Wq1[1], Pn1, 0, 0, 0);
          Pn2 = __builtin_amdgcn_mfma_i32_16x16x64_i8(AF0[s + 1], Wq2[0], Z, 0, 0, 0);
          Pn2 = __builtin_amdgcn_mfma_i32_16x16x64_i8(AF1[s + 1], Wq2[1], Pn2, 0, 0, 0);
        }
#pragma unroll
        for (int r = 0; r < 4; ++r) {
          int   P   = Pc1[r] * 252 + Pc2[r];         // exact, |P| < 2^23 (i24 mad)
          float cur = fmaf((float)P, inv2, b1v);
          float nv  = fmaf(BETA, v1[r], cur);
          bool  sp  = nv >= 1.0f;
          cnt[r] += sp ? 1 : 0;
          v1[r]  = sp ? 0.0f : nv;
        }
        if (s < GSTEP - 1) { Pc1 = Pn1; Pc2 = Pn2; }
      }
    }
    __syncthreads();
  }

  // ---- partial logits over this block's 64 n ----
  float* cnt_s = tbl;                       // reuse: 16 rows x 64 cols
  if (w >= 4) {
#pragma unroll
    for (int r = 0; r < 4; ++r)
      cnt_s[(quad * 4 + r) * 64 + (w - 4) * 16 + nl] = (float)cnt[r];
  }
  __syncthreads();
  if (tid < 16 * C_SZ) {
    int lb = tid / C_SZ, c = tid - lb * C_SZ;
    const float4* cr = (const float4*)(cnt_s + lb * 64);
    const float4* wr = (const float4*)(W_cls + c * H_SZ + NH * 64);
    float s = 0.0f;
#pragma unroll
    for (int i = 0; i < 16; ++i) {
      float4 a = cr[i], ww = wr[i];
      s += a.x * ww.x + a.y * ww.y + a.z * ww.z + a.w * ww.w;
    }
    part[(BG * 2 + NH) * 192 + lb * C_SZ + c] = s;
  }
}

// ---------------------------------------------------------------------------
// Kernel 3: combine the two n-half partials, scale, add bias.
__global__ void k_out(const float* __restrict__ part, const float* __restrict__ bc,
                      float* __restrict__ out) {
  int u = blockIdx.x * blockDim.x + threadIdx.x;
  if (u >= B_SZ * C_SZ) return;
  int b = u / C_SZ, c = u - b * C_SZ;
  int BG = b >> 4, lb = b & 15;
  float p = part[(BG * 2) * 192 + lb * C_SZ + c] +
            part[(BG * 2 + 1) * 192 + lb * C_SZ + c];
  out[u] = fmaf(p, 0.00390625f, bc[c]);
}

// ---------------------------------------------------------------------------
extern "C" void kernel_launch(void* const* d_in, const int* in_sizes, int n_in,
                              void* d_out, int out_size, void* d_ws, size_t ws_size,
                              hipStream_t stream) {
  (void)in_sizes; (void)n_in; (void)out_size; (void)ws_size;
  const int*   ids   = (const int*)d_in[0];
  const float* emb   = (const float*)d_in[1];
  const float* W_in  = (const float*)d_in[2];
  const float* b_in  = (const float*)d_in[3];
  const float* W_lif = (const float*)d_in[4];
  const float* b_lif = (const float*)d_in[5];
  // d_in[6] (W_rec) provably unused in forward
  const float* W_cls = (const float*)d_in[7];
  const float* b_cls = (const float*)d_in[8];
  float* out = (float*)d_out;

  float* table0p = (float*)d_ws;                       // 64 KB
  float* part    = (float*)((char*)d_ws + 65536);      // 256*192*4 = 192 KB

  k_table<<<V_SZ, H_SZ, 0, stream>>>(emb, W_in, b_in, W_lif, b_lif, table0p);
  k_fused<<<256, 512, 0, stream>>>(ids, table0p, W_lif + H_SZ * H_SZ, b_lif,
                                   W_cls, part);
  k_out<<<(B_SZ * C_SZ + 255) / 256, 256, 0, stream>>>(part, b_cls, out);
}

// Round 8
// 125.663 us; speedup vs baseline: 1.2598x; 1.0060x over previous
//
#include <hip/hip_runtime.h>

// RuleClassifierSNN — forward only, fused, wave-specialized producer/consumer.
//  * spike(post-reset v) == 0 always -> W_rec vanishes in forward.
//  * layer-0 drive is a V=128-entry lookup table (0.2f-folded) -> LDS,
//    row pitch 132 floats (bank decorrelation).
//  * layer-1 GEMM: spikes {0,1} as i8 in LDS; W as 2-plane i8 fixed point
//    (q1 + q2/252, per-row scale); exact i32 accumulate, P=252*P1+P2 exact.
//  * Spike rows are COLUMN-PERMUTED: c=8g+u maps to h = u<4 ? 4g+u : 64+4g+u-4,
//    so A-thread nl writes its 8 spike bytes as ONE ds_write_b64; the W-quant
//    k-index uses the same permutation (exact).
//  * 256 blocks x 512 thr. Block = 16 batches x 64 n (n-half by blockIdx&1).
//    Waves 0-3: layer-0 chains. Waves 4-7: one 16-n MFMA tile each.

#define T_STEPS 256
#define B_SZ    2048
#define H_SZ    128
#define V_SZ    128
#define E_SZ    64
#define C_SZ    12

typedef __attribute__((ext_vector_type(4))) int   i32x4;
typedef __attribute__((ext_vector_type(4))) float f32x4;

#define OMB  0.2f
#define BETA 0.8f

#define GSTEP  8
#define TPITCH 132                  // table row pitch (floats)
#define ROWP   144                  // spike row pitch (bytes)
#define STEPP  (16 * ROWP)          // 2304 B per step tile
#define GROUPP (GSTEP * STEPP)      // 18432 B per group buffer
#define IDP    260                  // ids row pitch (ints)

// ---------------------------------------------------------------------------
// Kernel 1: layer-0 lookup table. table0[v][h] = 0.2*((emb[v]@W_in.T+b_in)@W_lif0.T+b_lif0)
__global__ void k_table(const float* __restrict__ emb, const float* __restrict__ W_in,
                        const float* __restrict__ b_in, const float* __restrict__ W_lif0,
                        const float* __restrict__ b_lif0, float* __restrict__ table0p) {
  __shared__ float x1s[H_SZ];
  int v = blockIdx.x, h = threadIdx.x;
  float s = b_in[h];
  const float* er = emb + v * E_SZ;
  const float* wr = W_in + h * E_SZ;
#pragma unroll 8
  for (int e = 0; e < E_SZ; ++e) s += er[e] * wr[e];
  x1s[h] = s;
  __syncthreads();
  float t0 = b_lif0[h];
  const float* w0 = W_lif0 + h * H_SZ;
#pragma unroll 8
  for (int i = 0; i < H_SZ; ++i) t0 += x1s[i] * w0[i];
  table0p[v * H_SZ + h] = OMB * t0;
}

// ---------------------------------------------------------------------------
// Kernel 2: fused layer0 + layer1 + partial logits.
__launch_bounds__(512, 1)
__global__ void k_fused(const int* __restrict__ ids, const float* __restrict__ table0p,
                        const float* __restrict__ W1, const float* __restrict__ b_lif,
                        const float* __restrict__ W_cls, float* __restrict__ part) {
  __shared__ float tbl[V_SZ * TPITCH];                   // 67.6 KB
  __shared__ int   ids_s[16 * IDP];                      // 16.6 KB
  __shared__ __align__(16) signed char sb[2][GROUPP];    // 36.9 KB

  const int tid = threadIdx.x;
  const int BG  = blockIdx.x >> 1;      // batch group: batches [BG*16, BG*16+16)
  const int NH  = blockIdx.x & 1;       // n half: n in [NH*64, NH*64+64)
  const int lane = tid & 63, w = tid >> 6;
  const int nl = lane & 15, quad = lane >> 4;

  // ---- stage table (padded pitch) + ids ----
  {
    const float4* g4 = (const float4*)table0p;
#pragma unroll
    for (int i = 0; i < 8; ++i) {
      int idx4 = tid + i * 512;               // [0,4096)
      int v = idx4 >> 5, c = idx4 & 31;
      *(float4*)&tbl[v * TPITCH + c * 4] = g4[idx4];
    }
    const int* gi = ids + BG * 16 * T_STEPS;
#pragma unroll
    for (int i = 0; i < 8; ++i) {
      int idx = tid + i * 512;
      ids_s[(idx >> 8) * IDP + (idx & 255)] = gi[idx];
    }
  }

  // ---- A-wave state (waves 0-3): batch = w*4 + quad, 8 h per thread ----
  const int batch = w * 4 + quad;              // valid for w<4
  const int h0 = nl * 4;                       // h0..h0+3 and h0+64..h0+67
  const int* idrow = &ids_s[(batch & 15) * IDP];
  float va[4] = {0.f, 0.f, 0.f, 0.f};
  float vc[4] = {0.f, 0.f, 0.f, 0.f};

  auto a_group = [&](int gg, int buf) {
    const int tb = gg * GSTEP;
    int idv[GSTEP];
#pragma unroll
    for (int s = 0; s < GSTEP; ++s) idv[s] = idrow[tb + s];     // broadcast
    float4 ta[GSTEP], tc[GSTEP];
#pragma unroll
    for (int s = 0; s < GSTEP; ++s) {
      const float* tp = &tbl[idv[s] * TPITCH + h0];
      ta[s] = *(const float4*)tp;
      tc[s] = *(const float4*)(tp + 64);
    }
    // single b64 store per step: bytes c = nl*8 .. nl*8+7 (permuted columns)
    signed char* wb = &sb[buf][0] + batch * ROWP + nl * 8;
#pragma unroll
    for (int s = 0; s < GSTEP; ++s) {
      unsigned pa = 0, pb = 0;
      float nv;
      nv = fmaf(BETA, va[0], ta[s].x); pa |= (nv >= 1.f) ? 0x01u : 0u;       va[0] = (nv >= 1.f) ? 0.f : nv;
      nv = fmaf(BETA, va[1], ta[s].y); pa |= (nv >= 1.f) ? 0x0100u : 0u;     va[1] = (nv >= 1.f) ? 0.f : nv;
      nv = fmaf(BETA, va[2], ta[s].z); pa |= (nv >= 1.f) ? 0x010000u : 0u;   va[2] = (nv >= 1.f) ? 0.f : nv;
      nv = fmaf(BETA, va[3], ta[s].w); pa |= (nv >= 1.f) ? 0x01000000u : 0u; va[3] = (nv >= 1.f) ? 0.f : nv;
      nv = fmaf(BETA, vc[0], tc[s].x); pb |= (nv >= 1.f) ? 0x01u : 0u;       vc[0] = (nv >= 1.f) ? 0.f : nv;
      nv = fmaf(BETA, vc[1], tc[s].y); pb |= (nv >= 1.f) ? 0x0100u : 0u;     vc[1] = (nv >= 1.f) ? 0.f : nv;
      nv = fmaf(BETA, vc[2], tc[s].z); pb |= (nv >= 1.f) ? 0x010000u : 0u;   vc[2] = (nv >= 1.f) ? 0.f : nv;
      nv = fmaf(BETA, vc[3], tc[s].w); pb |= (nv >= 1.f) ? 0x01000000u : 0u; vc[3] = (nv >= 1.f) ? 0.f : nv;
      *(unsigned long long*)(wb + s * STEPP) =
          (unsigned long long)pa | ((unsigned long long)pb << 32);
    }
  };

  // ---- B-wave constants (waves 4-7): n = NH*64 + (w-4)*16 + nl ----
  i32x4 Wq1[2], Wq2[2];
  float inv2 = 0.f, b1v = 0.f;
  const int n = NH * 64 + (w - 4) * 16 + nl;   // valid for w>=4
  if (w >= 4) {
    const float* wrow = W1 + n * H_SZ;
    const float4* w4 = (const float4*)wrow;
    float mx = 1e-20f;
#pragma unroll
    for (int i = 0; i < 32; ++i) {
      float4 x = w4[i];
      mx = fmaxf(mx, fmaxf(fmaxf(fabsf(x.x), fabsf(x.y)), fmaxf(fabsf(x.z), fabsf(x.w))));
    }
    mx *= OMB;
    float S1 = 126.0f / mx, inv1 = 1.0f / S1;
    float S2 = S1 * 252.0f;
    inv2 = 1.0f / S2;
#pragma unroll
    for (int kt = 0; kt < 2; ++kt) {
      int q1w[4] = {0, 0, 0, 0}, q2w[4] = {0, 0, 0, 0};
#pragma unroll
      for (int jj = 0; jj < 16; ++jj) {
        // storage column -> original k (column permutation, see header)
        int c = kt * 64 + quad * 16 + jj;
        int g = c >> 3, u = c & 7;
        int k = (u < 4) ? (g * 4 + u) : (64 + g * 4 + (u - 4));
        float ww = OMB * wrow[k];
        float q1 = rintf(ww * S1);
        float r  = fmaf(-q1, inv1, ww);
        float q2 = rintf(r * S2);
        q1w[jj >> 2] |= ((int)q1 & 0xFF) << ((jj & 3) * 8);
        q2w[jj >> 2] |= ((int)q2 & 0xFF) << ((jj & 3) * 8);
      }
      Wq1[kt] = (i32x4){q1w[0], q1w[1], q1w[2], q1w[3]};
      Wq2[kt] = (i32x4){q2w[0], q2w[1], q2w[2], q2w[3]};
    }
    b1v = OMB * b_lif[H_SZ + n];
  }

  f32x4 v1 = {0.f, 0.f, 0.f, 0.f};
  int cnt[4] = {0, 0, 0, 0};
  const i32x4 Z = {0, 0, 0, 0};
  const signed char* const rbase = &sb[0][0] + nl * ROWP + quad * 16;

  __syncthreads();
  if (w < 4) a_group(0, 0);
  __syncthreads();

  for (int g = 0; g < T_STEPS / GSTEP; ++g) {
    if (w < 4) {
      if (g < T_STEPS / GSTEP - 1) a_group(g + 1, (g + 1) & 1);
    } else {
      const signed char* rp = rbase + (g & 1) * GROUPP;
      i32x4 AF0[GSTEP], AF1[GSTEP];
#pragma unroll
      for (int s = 0; s < GSTEP; ++s) {
        AF0[s] = *(const i32x4*)(rp + s * STEPP);
        AF1[s] = *(const i32x4*)(rp + s * STEPP + 64);
      }
      i32x4 Pc1 = __builtin_amdgcn_mfma_i32_16x16x64_i8(AF0[0], Wq1[0], Z, 0, 0, 0);
      Pc1       = __builtin_amdgcn_mfma_i32_16x16x64_i8(AF1[0], Wq1[1], Pc1, 0, 0, 0);
      i32x4 Pc2 = __builtin_amdgcn_mfma_i32_16x16x64_i8(AF0[0], Wq2[0], Z, 0, 0, 0);
      Pc2       = __builtin_amdgcn_mfma_i32_16x16x64_i8(AF1[0], Wq2[1], Pc2, 0, 0, 0);
#pragma unroll
      for (int s = 0; s < GSTEP; ++s) {
        i32x4 Pn1, Pn2;
        if (s < GSTEP - 1) {
          Pn1 = __builtin_amdgcn_mfma_i32_16x16x64_i8(AF0[s + 1], Wq1[0], Z, 0, 0, 0);
          Pn1 = __builtin_amdgcn_mfma_i32_16x16x64_i8(AF1[s + 1], Wq1[1], Pn1, 0, 0, 0);
          Pn2 = __builtin_amdgcn_mfma_i32_16x16x64_i8(AF0[s + 1], Wq2[0], Z, 0, 0, 0);
          Pn2 = __builtin_amdgcn_mfma_i32_16x16x64_i8(AF1[s + 1], Wq2[1], Pn2, 0, 0, 0);
        }
#pragma unroll
        for (int r = 0; r < 4; ++r) {
          int   P   = Pc1[r] * 252 + Pc2[r];         // exact, |P| < 2^23 (i24 mad)
          float cur = fmaf((float)P, inv2, b1v);
          float nv  = fmaf(BETA, v1[r], cur);
          bool  sp  = nv >= 1.0f;
          cnt[r] += sp ? 1 : 0;
          v1[r]  = sp ? 0.0f : nv;
        }
        if (s < GSTEP - 1) { Pc1 = Pn1; Pc2 = Pn2; }
      }
    }
    __syncthreads();
  }

  // ---- partial logits over this block's 64 n ----
  float* cnt_s = tbl;                       // reuse: 16 rows x 64 cols
  if (w >= 4) {
#pragma unroll
    for (int r = 0; r < 4; ++r)
      cnt_s[(quad * 4 + r) * 64 + (w - 4) * 16 + nl] = (float)cnt[r];
  }
  __syncthreads();
  if (tid < 16 * C_SZ) {
    int lb = tid / C_SZ, c = tid - lb * C_SZ;
    const float4* cr = (const float4*)(cnt_s + lb * 64);
    const float4* wr = (const float4*)(W_cls + c * H_SZ + NH * 64);
    float s = 0.0f;
#pragma unroll
    for (int i = 0; i < 16; ++i) {
      float4 a = cr[i], ww = wr[i];
      s += a.x * ww.x + a.y * ww.y + a.z * ww.z + a.w * ww.w;
    }
    part[(BG * 2 + NH) * 192 + lb * C_SZ + c] = s;
  }
}

// ---------------------------------------------------------------------------
// Kernel 3: combine the two n-half partials, scale, add bias.
__global__ void k_out(const float* __restrict__ part, const float* __restrict__ bc,
                      float* __restrict__ out) {
  int u = blockIdx.x * blockDim.x + threadIdx.x;
  if (u >= B_SZ * C_SZ) return;
  int b = u / C_SZ, c = u - b * C_SZ;
  int BG = b >> 4, lb = b & 15;
  float p = part[(BG * 2) * 192 + lb * C_SZ + c] +
            part[(BG * 2 + 1) * 192 + lb * C_SZ + c];
  out[u] = fmaf(p, 0.00390625f, bc[c]);
}

// ---------------------------------------------------------------------------
extern "C" void kernel_launch(void* const* d_in, const int* in_sizes, int n_in,
                              void* d_out, int out_size, void* d_ws, size_t ws_size,
                              hipStream_t stream) {
  (void)in_sizes; (void)n_in; (void)out_size; (void)ws_size;
  const int*   ids   = (const int*)d_in[0];
  const float* emb   = (const float*)d_in[1];
  const float* W_in  = (const float*)d_in[2];
  const float* b_in  = (const float*)d_in[3];
  const float* W_lif = (const float*)d_in[4];
  const float* b_lif = (const float*)d_in[5];
  // d_in[6] (W_rec) provably unused in forward
  const float* W_cls = (const float*)d_in[7];
  const float* b_cls = (const float*)d_in[8];
  float* out = (float*)d_out;

  float* table0p = (float*)d_ws;                       // 64 KB
  float* part    = (float*)((char*)d_ws + 65536);      // 192 KB

  k_table<<<V_SZ, H_SZ, 0, stream>>>(emb, W_in, b_in, W_lif, b_lif, table0p);
  k_fused<<<256, 512, 0, stream>>>(ids, table0p, W_lif + H_SZ * H_SZ, b_lif,
                                   W_cls, part);
  k_out<<<(B_SZ * C_SZ + 255) / 256, 256, 0, stream>>>(part, b_cls, out);
}

// Round 9
// 124.512 us; speedup vs baseline: 1.2714x; 1.0092x over previous
//
#include <hip/hip_runtime.h>

// RuleClassifierSNN — forward only, fused, wave-specialized producer/consumer.
//  * spike(post-reset v) == 0 always -> W_rec vanishes in forward.
//  * layer-0 drive is a V=128-entry lookup table (0.2f-folded) -> LDS.
//  * layer-1 GEMM: spikes {0,1} as i8 in LDS; W as 2-plane i8 fixed point
//    (q1 + q2/252, per-row scale); exact i32 accumulate, P=252*P1+P2 exact.
//  * 256 blocks x 768 thr (12 waves, 3/SIMD). Block = 16 batches x 64 n
//    (n-half by blockIdx&1). Waves 0-7: layer-0 chains (2 batches/wave,
//    4 h per thread -> 1 float4 read + 1 b32 store per step). Waves 8-11:
//    one 16-n MFMA tile each. G=8 steps/barrier, double-buffered spike tiles.
//    (R8's pitch-132 + column-permute reverted: measured regression.)

#define T_STEPS 256
#define B_SZ    2048
#define H_SZ    128
#define V_SZ    128
#define E_SZ    64
#define C_SZ    12

typedef __attribute__((ext_vector_type(4))) int   i32x4;
typedef __attribute__((ext_vector_type(4))) float f32x4;

#define OMB  0.2f
#define BETA 0.8f

#define GSTEP  8
#define ROWP   144                  // spike row pitch (bytes)
#define STEPP  (16 * ROWP)          // 2304 B per step tile
#define GROUPP (GSTEP * STEPP)      // 18432 B per group buffer
#define IDP    260                  // ids row pitch (ints)
#define NTHR   768

// ---------------------------------------------------------------------------
// Kernel 1: layer-0 lookup table. table0[v][h] = 0.2*((emb[v]@W_in.T+b_in)@W_lif0.T+b_lif0)
__global__ void k_table(const float* __restrict__ emb, const float* __restrict__ W_in,
                        const float* __restrict__ b_in, const float* __restrict__ W_lif0,
                        const float* __restrict__ b_lif0, float* __restrict__ table0p) {
  __shared__ float x1s[H_SZ];
  int v = blockIdx.x, h = threadIdx.x;
  float s = b_in[h];
  const float* er = emb + v * E_SZ;
  const float* wr = W_in + h * E_SZ;
#pragma unroll 8
  for (int e = 0; e < E_SZ; ++e) s += er[e] * wr[e];
  x1s[h] = s;
  __syncthreads();
  float t0 = b_lif0[h];
  const float* w0 = W_lif0 + h * H_SZ;
#pragma unroll 8
  for (int i = 0; i < H_SZ; ++i) t0 += x1s[i] * w0[i];
  table0p[v * H_SZ + h] = OMB * t0;
}

// ---------------------------------------------------------------------------
// Kernel 2: fused layer0 + layer1 + partial logits.
__launch_bounds__(NTHR, 1)
__global__ void k_fused(const int* __restrict__ ids, const float* __restrict__ table0p,
                        const float* __restrict__ W1, const float* __restrict__ b_lif,
                        const float* __restrict__ W_cls, float* __restrict__ part) {
  __shared__ float tbl[V_SZ * H_SZ];                     // 64 KB
  __shared__ int   ids_s[16 * IDP];                      // 16.6 KB
  __shared__ __align__(16) signed char sb[2][GROUPP];    // 36.9 KB

  const int tid = threadIdx.x;
  const int BG  = blockIdx.x >> 1;      // batch group: batches [BG*16, BG*16+16)
  const int NH  = blockIdx.x & 1;       // n half: n in [NH*64, NH*64+64)
  const int lane = tid & 63, w = tid >> 6;
  const int nl = lane & 15, quad = lane >> 4;

  // ---- stage table + ids (all threads, strided) ----
  {
    const float4* g4 = (const float4*)table0p;
    float4* t4 = (float4*)tbl;
    for (int idx = tid; idx < 4096; idx += NTHR) t4[idx] = g4[idx];
    const int* gi = ids + BG * 16 * T_STEPS;
    for (int idx = tid; idx < 4096; idx += NTHR)
      ids_s[(idx >> 8) * IDP + (idx & 255)] = gi[idx];
  }

  // ---- A-wave state (waves 0-7): batch = w*2 + (lane>>5), 4 h per thread ----
  const int batch = (w * 2 + (lane >> 5)) & 15;
  const int h0 = (lane & 31) * 4;              // h0..h0+3
  const int* idrow = &ids_s[batch * IDP];
  float va[4] = {0.f, 0.f, 0.f, 0.f};

  auto a_group = [&](int gg, int buf) {
    const int tb = gg * GSTEP;
    int idv[GSTEP];
#pragma unroll
    for (int s = 0; s < GSTEP; ++s) idv[s] = idrow[tb + s];     // broadcast
    float4 ta[GSTEP];
#pragma unroll
    for (int s = 0; s < GSTEP; ++s)
      ta[s] = *(const float4*)&tbl[idv[s] * H_SZ + h0];
    signed char* wb = &sb[buf][0] + batch * ROWP + h0;
#pragma unroll
    for (int s = 0; s < GSTEP; ++s) {
      unsigned pa = 0;
      float nv;
      nv = fmaf(BETA, va[0], ta[s].x); pa |= (nv >= 1.f) ? 0x01u : 0u;       va[0] = (nv >= 1.f) ? 0.f : nv;
      nv = fmaf(BETA, va[1], ta[s].y); pa |= (nv >= 1.f) ? 0x0100u : 0u;     va[1] = (nv >= 1.f) ? 0.f : nv;
      nv = fmaf(BETA, va[2], ta[s].z); pa |= (nv >= 1.f) ? 0x010000u : 0u;   va[2] = (nv >= 1.f) ? 0.f : nv;
      nv = fmaf(BETA, va[3], ta[s].w); pa |= (nv >= 1.f) ? 0x01000000u : 0u; va[3] = (nv >= 1.f) ? 0.f : nv;
      *(unsigned*)(wb + s * STEPP) = pa;
    }
  };

  // ---- B-wave constants (waves 8-11): n = NH*64 + (w-8)*16 + nl ----
  i32x4 Wq1[2], Wq2[2];
  float inv2 = 0.f, b1v = 0.f;
  const int n = NH * 64 + ((w - 8) & 3) * 16 + nl;
  if (w >= 8) {
    const float* wrow = W1 + n * H_SZ;
    const float4* w4 = (const float4*)wrow;
    float mx = 1e-20f;
#pragma unroll
    for (int i = 0; i < 32; ++i) {
      float4 x = w4[i];
      mx = fmaxf(mx, fmaxf(fmaxf(fabsf(x.x), fabsf(x.y)), fmaxf(fabsf(x.z), fabsf(x.w))));
    }
    mx *= OMB;
    float S1 = 126.0f / mx, inv1 = 1.0f / S1;
    float S2 = S1 * 252.0f;
    inv2 = 1.0f / S2;
#pragma unroll
    for (int kt = 0; kt < 2; ++kt) {
      int q1w[4] = {0, 0, 0, 0}, q2w[4] = {0, 0, 0, 0};
#pragma unroll
      for (int jj = 0; jj < 16; ++jj) {
        int k = kt * 64 + quad * 16 + jj;
        float ww = OMB * wrow[k];
        float q1 = rintf(ww * S1);
        float r  = fmaf(-q1, inv1, ww);
        float q2 = rintf(r * S2);
        q1w[jj >> 2] |= ((int)q1 & 0xFF) << ((jj & 3) * 8);
        q2w[jj >> 2] |= ((int)q2 & 0xFF) << ((jj & 3) * 8);
      }
      Wq1[kt] = (i32x4){q1w[0], q1w[1], q1w[2], q1w[3]};
      Wq2[kt] = (i32x4){q2w[0], q2w[1], q2w[2], q2w[3]};
    }
    b1v = OMB * b_lif[H_SZ + n];
  }

  f32x4 v1 = {0.f, 0.f, 0.f, 0.f};
  int cnt[4] = {0, 0, 0, 0};
  const i32x4 Z = {0, 0, 0, 0};
  const signed char* const rbase = &sb[0][0] + nl * ROWP + quad * 16;

  __syncthreads();
  if (w < 8) a_group(0, 0);
  __syncthreads();

  for (int g = 0; g < T_STEPS / GSTEP; ++g) {
    if (w < 8) {
      if (g < T_STEPS / GSTEP - 1) a_group(g + 1, (g + 1) & 1);
    } else {
      const signed char* rp = rbase + (g & 1) * GROUPP;
      i32x4 AF0[GSTEP], AF1[GSTEP];
#pragma unroll
      for (int s = 0; s < GSTEP; ++s) {
        AF0[s] = *(const i32x4*)(rp + s * STEPP);
        AF1[s] = *(const i32x4*)(rp + s * STEPP + 64);
      }
      i32x4 Pc1 = __builtin_amdgcn_mfma_i32_16x16x64_i8(AF0[0], Wq1[0], Z, 0, 0, 0);
      Pc1       = __builtin_amdgcn_mfma_i32_16x16x64_i8(AF1[0], Wq1[1], Pc1, 0, 0, 0);
      i32x4 Pc2 = __builtin_amdgcn_mfma_i32_16x16x64_i8(AF0[0], Wq2[0], Z, 0, 0, 0);
      Pc2       = __builtin_amdgcn_mfma_i32_16x16x64_i8(AF1[0], Wq2[1], Pc2, 0, 0, 0);
#pragma unroll
      for (int s = 0; s < GSTEP; ++s) {
        i32x4 Pn1, Pn2;
        if (s < GSTEP - 1) {
          Pn1 = __builtin_amdgcn_mfma_i32_16x16x64_i8(AF0[s + 1], Wq1[0], Z, 0, 0, 0);
          Pn1 = __builtin_amdgcn_mfma_i32_16x16x64_i8(AF1[s + 1], Wq1[1], Pn1, 0, 0, 0);
          Pn2 = __builtin_amdgcn_mfma_i32_16x16x64_i8(AF0[s + 1], Wq2[0], Z, 0, 0, 0);
          Pn2 = __builtin_amdgcn_mfma_i32_16x16x64_i8(AF1[s + 1], Wq2[1], Pn2, 0, 0, 0);
        }
#pragma unroll
        for (int r = 0; r < 4; ++r) {
          int   P   = Pc1[r] * 252 + Pc2[r];         // exact, |P| < 2^23 (i24 mad)
          float cur = fmaf((float)P, inv2, b1v);
          float nv  = fmaf(BETA, v1[r], cur);
          bool  sp  = nv >= 1.0f;
          cnt[r] += sp ? 1 : 0;
          v1[r]  = sp ? 0.0f : nv;
        }
        if (s < GSTEP - 1) { Pc1 = Pn1; Pc2 = Pn2; }
      }
    }
    __syncthreads();
  }

  // ---- partial logits over this block's 64 n ----
  float* cnt_s = tbl;                       // reuse: 16 rows x 64 cols
  if (w >= 8) {
#pragma unroll
    for (int r = 0; r < 4; ++r)
      cnt_s[(quad * 4 + r) * 64 + ((w - 8) & 3) * 16 + nl] = (float)cnt[r];
  }
  __syncthreads();
  if (tid < 16 * C_SZ) {
    int lb = tid / C_SZ, c = tid - lb * C_SZ;
    const float4* cr = (const float4*)(cnt_s + lb * 64);
    const float4* wr = (const float4*)(W_cls + c * H_SZ + NH * 64);
    float s = 0.0f;
#pragma unroll
    for (int i = 0; i < 16; ++i) {
      float4 a = cr[i], ww = wr[i];
      s += a.x * ww.x + a.y * ww.y + a.z * ww.z + a.w * ww.w;
    }
    part[(BG * 2 + NH) * 192 + lb * C_SZ + c] = s;
  }
}

// ---------------------------------------------------------------------------
// Kernel 3: combine the two n-half partials, scale, add bias.
__global__ void k_out(const float* __restrict__ part, const float* __restrict__ bc,
                      float* __restrict__ out) {
  int u = blockIdx.x * blockDim.x + threadIdx.x;
  if (u >= B_SZ * C_SZ) return;
  int b = u / C_SZ, c = u - b * C_SZ;
  int BG = b >> 4, lb = b & 15;
  float p = part[(BG * 2) * 192 + lb * C_SZ + c] +
            part[(BG * 2 + 1) * 192 + lb * C_SZ + c];
  out[u] = fmaf(p, 0.00390625f, bc[c]);
}

// ---------------------------------------------------------------------------
extern "C" void kernel_launch(void* const* d_in, const int* in_sizes, int n_in,
                              void* d_out, int out_size, void* d_ws, size_t ws_size,
                              hipStream_t stream) {
  (void)in_sizes; (void)n_in; (void)out_size; (void)ws_size;
  const int*   ids   = (const int*)d_in[0];
  const float* emb   = (const float*)d_in[1];
  const float* W_in  = (const float*)d_in[2];
  const float* b_in  = (const float*)d_in[3];
  const float* W_lif = (const float*)d_in[4];
  const float* b_lif = (const float*)d_in[5];
  // d_in[6] (W_rec) provably unused in forward
  const float* W_cls = (const float*)d_in[7];
  const float* b_cls = (const float*)d_in[8];
  float* out = (float*)d_out;

  float* table0p = (float*)d_ws;                       // 64 KB
  float* part    = (float*)((char*)d_ws + 65536);      // 192 KB

  k_table<<<V_SZ, H_SZ, 0, stream>>>(emb, W_in, b_in, W_lif, b_lif, table0p);
  k_fused<<<256, NTHR, 0, stream>>>(ids, table0p, W_lif + H_SZ * H_SZ, b_lif,
                                    W_cls, part);
  k_out<<<(B_SZ * C_SZ + 255) / 256, 256, 0, stream>>>(part, b_cls, out);
}

// Round 11
// 124.450 us; speedup vs baseline: 1.2721x; 1.0005x over previous
//
#include <hip/hip_runtime.h>

// RuleClassifierSNN — forward only, fused, flag-synchronized producer/consumer.
//  * spike(post-reset v) == 0 always -> W_rec vanishes in forward.
//  * layer-0 drive is a V=128-entry lookup table (0.2f-folded), kept in
//    GLOBAL memory (64KB, L1/L2-resident) — LDS holds only ids + spike ring.
//  * layer-1 GEMM: spikes {0,1} as i8 in LDS; W as 2-plane i8 fixed point
//    (q1 + q2/252, per-row scale); exact i32 accumulate, P=252*P1+P2 exact.
//  * 256 blocks x 768 thr. Block = 16 batches x 64 n (n-half by blockIdx&1).
//    Waves 0-7: layer-0 chains. Waves 8-11: one 16-n MFMA tile each.
//    No __syncthreads in hot loop: NBUF=3 ring + LDS prod/cons counters.
//  * R10 bugfix: counters are incremented by LANE 0 ONLY (per-lane atomics
//    inflated counts 64x and broke the handshake -> stale reads).

#define T_STEPS 256
#define B_SZ    2048
#define H_SZ    128
#define V_SZ    128
#define E_SZ    64
#define C_SZ    12

typedef __attribute__((ext_vector_type(4))) int   i32x4;
typedef __attribute__((ext_vector_type(4))) float f32x4;

#define OMB  0.2f
#define BETA 0.8f

#define GSTEP  8
#define NBUF   3
#define NGRP   (T_STEPS / GSTEP)    // 32
#define ROWP   144                  // spike row pitch (bytes)
#define STEPP  (16 * ROWP)          // 2304 B per step tile
#define GROUPP (GSTEP * STEPP)      // 18432 B per group buffer
#define IDP    260                  // ids row pitch (ints)
#define NTHR   768

// ---------------------------------------------------------------------------
// Kernel 1: build layer-0 lookup table + init out with bias.
__global__ void k_table(const float* __restrict__ emb, const float* __restrict__ W_in,
                        const float* __restrict__ b_in, const float* __restrict__ W_lif0,
                        const float* __restrict__ b_lif0, const float* __restrict__ b_cls,
                        float* __restrict__ table0p, float* __restrict__ out) {
  __shared__ float x1s[H_SZ];
  int v = blockIdx.x, h = threadIdx.x;
  float s = b_in[h];
  const float* er = emb + v * E_SZ;
  const float* wr = W_in + h * E_SZ;
#pragma unroll 8
  for (int e = 0; e < E_SZ; ++e) s += er[e] * wr[e];
  x1s[h] = s;
  __syncthreads();
  float t0 = b_lif0[h];
  const float* w0 = W_lif0 + h * H_SZ;
#pragma unroll 8
  for (int i = 0; i < H_SZ; ++i) t0 += x1s[i] * w0[i];
  table0p[v * H_SZ + h] = OMB * t0;
  // out init: 192 elements per block (128 blocks x 192 = 24576 = 2048*12)
  int u = v * 192 + h;
  out[u] = b_cls[u % C_SZ];
  if (h < 64) { int u2 = u + 128; out[u2] = b_cls[u2 % C_SZ]; }
}

// ---------------------------------------------------------------------------
// Kernel 2: fused layer0 + layer1 + logits (atomic partial accumulate).
__launch_bounds__(NTHR, 3)
__global__ void k_fused(const int* __restrict__ ids, const float* __restrict__ table0p,
                        const float* __restrict__ W1, const float* __restrict__ b_lif,
                        const float* __restrict__ W_cls, float* __restrict__ out) {
  __shared__ int   ids_s[16 * IDP];                      // 16.6 KB
  __shared__ __align__(16) signed char sb[NBUF][GROUPP]; // 55.3 KB
  __shared__ int prodc[NBUF], consc[NBUF];

  const int tid = threadIdx.x;
  const int BG  = blockIdx.x >> 1;      // batches [BG*16, BG*16+16)
  const int NH  = blockIdx.x & 1;       // n in [NH*64, NH*64+64)
  const int lane = tid & 63, w = tid >> 6;
  const int nl = lane & 15, quad = lane >> 4;

  if (tid < NBUF) { prodc[tid] = 0; consc[tid] = 0; }
  {
    const int* gi = ids + BG * 16 * T_STEPS;
    for (int idx = tid; idx < 4096; idx += NTHR)
      ids_s[(idx >> 8) * IDP + (idx & 255)] = gi[idx];
  }

  // ---- B-wave weight setup (waves 8-11), before the one barrier ----
  i32x4 Wq1[2], Wq2[2];
  float inv2 = 0.f, b1v = 0.f;
  const int n = NH * 64 + ((w - 8) & 3) * 16 + nl;
  if (w >= 8) {
    const float* wrow = W1 + n * H_SZ;
    const float4* w4 = (const float4*)wrow;
    float mx = 1e-20f;
#pragma unroll
    for (int i = 0; i < 32; ++i) {
      float4 x = w4[i];
      mx = fmaxf(mx, fmaxf(fmaxf(fabsf(x.x), fabsf(x.y)), fmaxf(fabsf(x.z), fabsf(x.w))));
    }
    mx *= OMB;
    float S1 = 126.0f / mx, inv1 = 1.0f / S1;
    float S2 = S1 * 252.0f;
    inv2 = 1.0f / S2;
#pragma unroll
    for (int kt = 0; kt < 2; ++kt) {
      int q1w[4] = {0, 0, 0, 0}, q2w[4] = {0, 0, 0, 0};
#pragma unroll
      for (int jj = 0; jj < 16; ++jj) {
        int k = kt * 64 + quad * 16 + jj;
        float ww = OMB * wrow[k];
        float q1 = rintf(ww * S1);
        float r  = fmaf(-q1, inv1, ww);
        float q2 = rintf(r * S2);
        q1w[jj >> 2] |= ((int)q1 & 0xFF) << ((jj & 3) * 8);
        q2w[jj >> 2] |= ((int)q2 & 0xFF) << ((jj & 3) * 8);
      }
      Wq1[kt] = (i32x4){q1w[0], q1w[1], q1w[2], q1w[3]};
      Wq2[kt] = (i32x4){q2w[0], q2w[1], q2w[2], q2w[3]};
    }
    b1v = OMB * b_lif[H_SZ + n];
  }

  __syncthreads();   // ids_s + flags published; last barrier before hot loop

  int cnt[4] = {0, 0, 0, 0};

  if (w < 8) {
    // ================= A role: layer-0 chains =================
    const int batch = (w * 2 + (lane >> 5)) & 15;
    const int h0 = (lane & 31) * 4;
    const int* idrow = &ids_s[batch * IDP];
    const float* tb0 = table0p + h0;
    float va[4] = {0.f, 0.f, 0.f, 0.f};
    for (int g = 0; g < NGRP; ++g) {
      const int p = g % NBUF, m = g / NBUF;
      if (m > 0) {
        while (__hip_atomic_load(&consc[p], __ATOMIC_ACQUIRE,
                                 __HIP_MEMORY_SCOPE_WORKGROUP) < 4 * m)
          __builtin_amdgcn_s_sleep(1);
      }
      const int tb = g * GSTEP;
      float4 ta[GSTEP];
#pragma unroll
      for (int s = 0; s < GSTEP; ++s) {
        int idv = idrow[tb + s];
        ta[s] = *(const float4*)(tb0 + idv * H_SZ);    // global gather (L1/L2)
      }
      signed char* wb = &sb[p][0] + batch * ROWP + h0;
#pragma unroll
      for (int s = 0; s < GSTEP; ++s) {
        unsigned pa = 0;
        float nv;
        nv = fmaf(BETA, va[0], ta[s].x); pa |= (nv >= 1.f) ? 0x01u : 0u;       va[0] = (nv >= 1.f) ? 0.f : nv;
        nv = fmaf(BETA, va[1], ta[s].y); pa |= (nv >= 1.f) ? 0x0100u : 0u;     va[1] = (nv >= 1.f) ? 0.f : nv;
        nv = fmaf(BETA, va[2], ta[s].z); pa |= (nv >= 1.f) ? 0x010000u : 0u;   va[2] = (nv >= 1.f) ? 0.f : nv;
        nv = fmaf(BETA, va[3], ta[s].w); pa |= (nv >= 1.f) ? 0x01000000u : 0u; va[3] = (nv >= 1.f) ? 0.f : nv;
        *(unsigned*)(wb + s * STEPP) = pa;
      }
      if (lane == 0)
        __hip_atomic_fetch_add(&prodc[p], 1, __ATOMIC_RELEASE,
                               __HIP_MEMORY_SCOPE_WORKGROUP);
    }
  } else {
    // ================= B role: layer-1 MFMA scan =================
    f32x4 v1 = {0.f, 0.f, 0.f, 0.f};
    const i32x4 Z = {0, 0, 0, 0};
    const signed char* const rb = &sb[0][0] + nl * ROWP + quad * 16;
    for (int g = 0; g < NGRP; ++g) {
      const int p = g % NBUF, m = g / NBUF;
      while (__hip_atomic_load(&prodc[p], __ATOMIC_ACQUIRE,
                               __HIP_MEMORY_SCOPE_WORKGROUP) < 8 * (m + 1))
        __builtin_amdgcn_s_sleep(1);
      const signed char* rp = rb + p * GROUPP;
      i32x4 AF0[GSTEP], AF1[GSTEP];
#pragma unroll
      for (int s = 0; s < GSTEP; ++s) {
        AF0[s] = *(const i32x4*)(rp + s * STEPP);
        AF1[s] = *(const i32x4*)(rp + s * STEPP + 64);
      }
      i32x4 Pc1 = __builtin_amdgcn_mfma_i32_16x16x64_i8(AF0[0], Wq1[0], Z, 0, 0, 0);
      Pc1       = __builtin_amdgcn_mfma_i32_16x16x64_i8(AF1[0], Wq1[1], Pc1, 0, 0, 0);
      i32x4 Pc2 = __builtin_amdgcn_mfma_i32_16x16x64_i8(AF0[0], Wq2[0], Z, 0, 0, 0);
      Pc2       = __builtin_amdgcn_mfma_i32_16x16x64_i8(AF1[0], Wq2[1], Pc2, 0, 0, 0);
#pragma unroll
      for (int s = 0; s < GSTEP; ++s) {
        i32x4 Pn1, Pn2;
        if (s < GSTEP - 1) {
          Pn1 = __builtin_amdgcn_mfma_i32_16x16x64_i8(AF0[s + 1], Wq1[0], Z, 0, 0, 0);
          Pn1 = __builtin_amdgcn_mfma_i32_16x16x64_i8(AF1[s + 1], Wq1[1], Pn1, 0, 0, 0);
          Pn2 = __builtin_amdgcn_mfma_i32_16x16x64_i8(AF0[s + 1], Wq2[0], Z, 0, 0, 0);
          Pn2 = __builtin_amdgcn_mfma_i32_16x16x64_i8(AF1[s + 1], Wq2[1], Pn2, 0, 0, 0);
        }
#pragma unroll
        for (int r = 0; r < 4; ++r) {
          int   P   = Pc1[r] * 252 + Pc2[r];         // exact, |P| < 2^23
          float cur = fmaf((float)P, inv2, b1v);
          float nv  = fmaf(BETA, v1[r], cur);
          bool  sp  = nv >= 1.0f;
          cnt[r] += sp ? 1 : 0;
          v1[r]  = sp ? 0.0f : nv;
        }
        if (s < GSTEP - 1) { Pc1 = Pn1; Pc2 = Pn2; }
      }
      if (lane == 0)
        __hip_atomic_fetch_add(&consc[p], 1, __ATOMIC_RELEASE,
                               __HIP_MEMORY_SCOPE_WORKGROUP);
    }
  }

  // ---- partial logits over this block's 64 n (atomicAdd into out) ----
  __syncthreads();
  float* cnt_s = (float*)&sb[0][0];                 // 16 x 64 floats
  if (w >= 8) {
#pragma unroll
    for (int r = 0; r < 4; ++r)
      cnt_s[(quad * 4 + r) * 64 + ((w - 8) & 3) * 16 + nl] = (float)cnt[r];
  }
  __syncthreads();
  if (tid < 16 * C_SZ) {
    int lb = tid / C_SZ, c = tid - lb * C_SZ;
    const float4* cr = (const float4*)(cnt_s + lb * 64);
    const float4* wr = (const float4*)(W_cls + c * H_SZ + NH * 64);
    float s = 0.0f;
#pragma unroll
    for (int i = 0; i < 16; ++i) {
      float4 a = cr[i], ww = wr[i];
      s += a.x * ww.x + a.y * ww.y + a.z * ww.z + a.w * ww.w;
    }
    atomicAdd(&out[(BG * 16 + lb) * C_SZ + c], s * 0.00390625f);
  }
}

// ---------------------------------------------------------------------------
extern "C" void kernel_launch(void* const* d_in, const int* in_sizes, int n_in,
                              void* d_out, int out_size, void* d_ws, size_t ws_size,
                              hipStream_t stream) {
  (void)in_sizes; (void)n_in; (void)out_size; (void)ws_size;
  const int*   ids   = (const int*)d_in[0];
  const float* emb   = (const float*)d_in[1];
  const float* W_in  = (const float*)d_in[2];
  const float* b_in  = (const float*)d_in[3];
  const float* W_lif = (const float*)d_in[4];
  const float* b_lif = (const float*)d_in[5];
  // d_in[6] (W_rec) provably unused in forward
  const float* W_cls = (const float*)d_in[7];
  const float* b_cls = (const float*)d_in[8];
  float* out = (float*)d_out;

  float* table0p = (float*)d_ws;                       // 64 KB

  k_table<<<V_SZ, H_SZ, 0, stream>>>(emb, W_in, b_in, W_lif, b_lif, b_cls,
                                     table0p, out);
  k_fused<<<256, NTHR, 0, stream>>>(ids, table0p, W_lif + H_SZ * H_SZ, b_lif,
                                    W_cls, out);
}

// Round 12
// 122.864 us; speedup vs baseline: 1.2885x; 1.0129x over previous
//
#include <hip/hip_runtime.h>

// RuleClassifierSNN — forward only, fused, wave-specialized producer/consumer.
//  * spike(post-reset v) == 0 always -> W_rec vanishes in forward.
//  * layer-0 drive is a V=128-entry lookup table (0.2f-folded) -> LDS.
//  * layer-1 GEMM: spikes {0,1} as i8 in LDS; W as 2-plane i8 fixed point
//    (q1 + q2/252, per-row scale); exact i32 accumulate, P=252*P1+P2 exact.
//  * 256 blocks x 768 thr (12 waves, 3/SIMD). Block = 16 batches x 64 n
//    (n-half by blockIdx&1). Waves 0-7: layer-0 chains (2 batches/wave,
//    4 h/thread). Waves 8-11: one 16-n MFMA tile each. G=8 steps/barrier,
//    double-buffered spike tiles. (R11's flag protocol + global table
//    reverted: measured 62 vs 54.3 us — barrier was never the limiter.)
//  * 2 kernels only: k_table bias-inits out; k_fused atomicAdds partials.

#define T_STEPS 256
#define B_SZ    2048
#define H_SZ    128
#define V_SZ    128
#define E_SZ    64
#define C_SZ    12

typedef __attribute__((ext_vector_type(4))) int   i32x4;
typedef __attribute__((ext_vector_type(4))) float f32x4;

#define OMB  0.2f
#define BETA 0.8f

#define GSTEP  8
#define ROWP   144                  // spike row pitch (bytes)
#define STEPP  (16 * ROWP)          // 2304 B per step tile
#define GROUPP (GSTEP * STEPP)      // 18432 B per group buffer
#define IDP    260                  // ids row pitch (ints)
#define NTHR   768

// ---------------------------------------------------------------------------
// Kernel 1: layer-0 lookup table + bias-init of out.
__global__ void k_table(const float* __restrict__ emb, const float* __restrict__ W_in,
                        const float* __restrict__ b_in, const float* __restrict__ W_lif0,
                        const float* __restrict__ b_lif0, const float* __restrict__ b_cls,
                        float* __restrict__ table0p, float* __restrict__ out) {
  __shared__ float x1s[H_SZ];
  int v = blockIdx.x, h = threadIdx.x;
  float s = b_in[h];
  const float* er = emb + v * E_SZ;
  const float* wr = W_in + h * E_SZ;
#pragma unroll 8
  for (int e = 0; e < E_SZ; ++e) s += er[e] * wr[e];
  x1s[h] = s;
  __syncthreads();
  float t0 = b_lif0[h];
  const float* w0 = W_lif0 + h * H_SZ;
#pragma unroll 8
  for (int i = 0; i < H_SZ; ++i) t0 += x1s[i] * w0[i];
  table0p[v * H_SZ + h] = OMB * t0;
  // out init with bias: 192 elems/block x 128 blocks = 24576 = 2048*12
  int u = v * 192 + h;
  out[u] = b_cls[u % C_SZ];
  if (h < 64) { int u2 = u + 128; out[u2] = b_cls[u2 % C_SZ]; }
}

// ---------------------------------------------------------------------------
// Kernel 2: fused layer0 + layer1 + logits (atomicAdd partials into out).
__launch_bounds__(NTHR, 1)
__global__ void k_fused(const int* __restrict__ ids, const float* __restrict__ table0p,
                        const float* __restrict__ W1, const float* __restrict__ b_lif,
                        const float* __restrict__ W_cls, float* __restrict__ out) {
  __shared__ float tbl[V_SZ * H_SZ];                     // 64 KB
  __shared__ int   ids_s[16 * IDP];                      // 16.6 KB
  __shared__ __align__(16) signed char sb[2][GROUPP];    // 36.9 KB

  const int tid = threadIdx.x;
  const int BG  = blockIdx.x >> 1;      // batches [BG*16, BG*16+16)
  const int NH  = blockIdx.x & 1;       // n in [NH*64, NH*64+64)
  const int lane = tid & 63, w = tid >> 6;
  const int nl = lane & 15, quad = lane >> 4;

  // ---- stage table + ids ----
  {
    const float4* g4 = (const float4*)table0p;
    float4* t4 = (float4*)tbl;
    for (int idx = tid; idx < 4096; idx += NTHR) t4[idx] = g4[idx];
    const int* gi = ids + BG * 16 * T_STEPS;
    for (int idx = tid; idx < 4096; idx += NTHR)
      ids_s[(idx >> 8) * IDP + (idx & 255)] = gi[idx];
  }

  // ---- A-wave state (waves 0-7): batch = w*2 + (lane>>5), 4 h per thread ----
  const int batch = (w * 2 + (lane >> 5)) & 15;
  const int h0 = (lane & 31) * 4;
  const int* idrow = &ids_s[batch * IDP];
  float va[4] = {0.f, 0.f, 0.f, 0.f};

  auto a_group = [&](int gg, int buf) {
    const int tb = gg * GSTEP;
    int idv[GSTEP];
#pragma unroll
    for (int s = 0; s < GSTEP; ++s) idv[s] = idrow[tb + s];     // broadcast
    float4 ta[GSTEP];
#pragma unroll
    for (int s = 0; s < GSTEP; ++s)
      ta[s] = *(const float4*)&tbl[idv[s] * H_SZ + h0];
    signed char* wb = &sb[buf][0] + batch * ROWP + h0;
#pragma unroll
    for (int s = 0; s < GSTEP; ++s) {
      unsigned pa = 0;
      float nv;
      nv = fmaf(BETA, va[0], ta[s].x); pa |= (nv >= 1.f) ? 0x01u : 0u;       va[0] = (nv >= 1.f) ? 0.f : nv;
      nv = fmaf(BETA, va[1], ta[s].y); pa |= (nv >= 1.f) ? 0x0100u : 0u;     va[1] = (nv >= 1.f) ? 0.f : nv;
      nv = fmaf(BETA, va[2], ta[s].z); pa |= (nv >= 1.f) ? 0x010000u : 0u;   va[2] = (nv >= 1.f) ? 0.f : nv;
      nv = fmaf(BETA, va[3], ta[s].w); pa |= (nv >= 1.f) ? 0x01000000u : 0u; va[3] = (nv >= 1.f) ? 0.f : nv;
      *(unsigned*)(wb + s * STEPP) = pa;
    }
  };

  // ---- B-wave constants (waves 8-11): n = NH*64 + (w-8)*16 + nl ----
  i32x4 Wq1[2], Wq2[2];
  float inv2 = 0.f, b1v = 0.f;
  const int n = NH * 64 + ((w - 8) & 3) * 16 + nl;
  if (w >= 8) {
    const float* wrow = W1 + n * H_SZ;
    const float4* w4 = (const float4*)wrow;
    float mx = 1e-20f;
#pragma unroll
    for (int i = 0; i < 32; ++i) {
      float4 x = w4[i];
      mx = fmaxf(mx, fmaxf(fmaxf(fabsf(x.x), fabsf(x.y)), fmaxf(fabsf(x.z), fabsf(x.w))));
    }
    mx *= OMB;
    float S1 = 126.0f / mx, inv1 = 1.0f / S1;
    float S2 = S1 * 252.0f;
    inv2 = 1.0f / S2;
#pragma unroll
    for (int kt = 0; kt < 2; ++kt) {
      int q1w[4] = {0, 0, 0, 0}, q2w[4] = {0, 0, 0, 0};
#pragma unroll
      for (int jj = 0; jj < 16; ++jj) {
        int k = kt * 64 + quad * 16 + jj;
        float ww = OMB * wrow[k];
        float q1 = rintf(ww * S1);
        float r  = fmaf(-q1, inv1, ww);
        float q2 = rintf(r * S2);
        q1w[jj >> 2] |= ((int)q1 & 0xFF) << ((jj & 3) * 8);
        q2w[jj >> 2] |= ((int)q2 & 0xFF) << ((jj & 3) * 8);
      }
      Wq1[kt] = (i32x4){q1w[0], q1w[1], q1w[2], q1w[3]};
      Wq2[kt] = (i32x4){q2w[0], q2w[1], q2w[2], q2w[3]};
    }
    b1v = OMB * b_lif[H_SZ + n];
  }

  f32x4 v1 = {0.f, 0.f, 0.f, 0.f};
  int cnt[4] = {0, 0, 0, 0};
  const i32x4 Z = {0, 0, 0, 0};
  const signed char* const rbase = &sb[0][0] + nl * ROWP + quad * 16;

  __syncthreads();
  if (w < 8) a_group(0, 0);
  __syncthreads();

  for (int g = 0; g < T_STEPS / GSTEP; ++g) {
    if (w < 8) {
      if (g < T_STEPS / GSTEP - 1) a_group(g + 1, (g + 1) & 1);
    } else {
      const signed char* rp = rbase + (g & 1) * GROUPP;
      i32x4 AF0[GSTEP], AF1[GSTEP];
#pragma unroll
      for (int s = 0; s < GSTEP; ++s) {
        AF0[s] = *(const i32x4*)(rp + s * STEPP);
        AF1[s] = *(const i32x4*)(rp + s * STEPP + 64);
      }
      i32x4 Pc1 = __builtin_amdgcn_mfma_i32_16x16x64_i8(AF0[0], Wq1[0], Z, 0, 0, 0);
      Pc1       = __builtin_amdgcn_mfma_i32_16x16x64_i8(AF1[0], Wq1[1], Pc1, 0, 0, 0);
      i32x4 Pc2 = __builtin_amdgcn_mfma_i32_16x16x64_i8(AF0[0], Wq2[0], Z, 0, 0, 0);
      Pc2       = __builtin_amdgcn_mfma_i32_16x16x64_i8(AF1[0], Wq2[1], Pc2, 0, 0, 0);
#pragma unroll
      for (int s = 0; s < GSTEP; ++s) {
        i32x4 Pn1, Pn2;
        if (s < GSTEP - 1) {
          Pn1 = __builtin_amdgcn_mfma_i32_16x16x64_i8(AF0[s + 1], Wq1[0], Z, 0, 0, 0);
          Pn1 = __builtin_amdgcn_mfma_i32_16x16x64_i8(AF1[s + 1], Wq1[1], Pn1, 0, 0, 0);
          Pn2 = __builtin_amdgcn_mfma_i32_16x16x64_i8(AF0[s + 1], Wq2[0], Z, 0, 0, 0);
          Pn2 = __builtin_amdgcn_mfma_i32_16x16x64_i8(AF1[s + 1], Wq2[1], Pn2, 0, 0, 0);
        }
#pragma unroll
        for (int r = 0; r < 4; ++r) {
          int   P   = Pc1[r] * 252 + Pc2[r];         // exact, |P| < 2^23 (i24 mad)
          float cur = fmaf((float)P, inv2, b1v);
          float nv  = fmaf(BETA, v1[r], cur);
          bool  sp  = nv >= 1.0f;
          cnt[r] += sp ? 1 : 0;
          v1[r]  = sp ? 0.0f : nv;
        }
        if (s < GSTEP - 1) { Pc1 = Pn1; Pc2 = Pn2; }
      }
    }
    __syncthreads();
  }

  // ---- partial logits over this block's 64 n (atomicAdd into out) ----
  float* cnt_s = tbl;                       // reuse: 16 rows x 64 cols
  if (w >= 8) {
#pragma unroll
    for (int r = 0; r < 4; ++r)
      cnt_s[(quad * 4 + r) * 64 + ((w - 8) & 3) * 16 + nl] = (float)cnt[r];
  }
  __syncthreads();
  if (tid < 16 * C_SZ) {
    int lb = tid / C_SZ, c = tid - lb * C_SZ;
    const float4* cr = (const float4*)(cnt_s + lb * 64);
    const float4* wr = (const float4*)(W_cls + c * H_SZ + NH * 64);
    float s = 0.0f;
#pragma unroll
    for (int i = 0; i < 16; ++i) {
      float4 a = cr[i], ww = wr[i];
      s += a.x * ww.x + a.y * ww.y + a.z * ww.z + a.w * ww.w;
    }
    atomicAdd(&out[(BG * 16 + lb) * C_SZ + c], s * 0.00390625f);
  }
}

// ---------------------------------------------------------------------------
extern "C" void kernel_launch(void* const* d_in, const int* in_sizes, int n_in,
                              void* d_out, int out_size, void* d_ws, size_t ws_size,
                              hipStream_t stream) {
  (void)in_sizes; (void)n_in; (void)out_size; (void)ws_size;
  const int*   ids   = (const int*)d_in[0];
  const float* emb   = (const float*)d_in[1];
  const float* W_in  = (const float*)d_in[2];
  const float* b_in  = (const float*)d_in[3];
  const float* W_lif = (const float*)d_in[4];
  const float* b_lif = (const float*)d_in[5];
  // d_in[6] (W_rec) provably unused in forward
  const float* W_cls = (const float*)d_in[7];
  const float* b_cls = (const float*)d_in[8];
  float* out = (float*)d_out;

  float* table0p = (float*)d_ws;                       // 64 KB

  k_table<<<V_SZ, H_SZ, 0, stream>>>(emb, W_in, b_in, W_lif, b_lif, b_cls,
                                     table0p, out);
  k_fused<<<256, NTHR, 0, stream>>>(ids, table0p, W_lif + H_SZ * H_SZ, b_lif,
                                    W_cls, out);
}

// Round 13
// 77.732 us; speedup vs baseline: 2.0366x; 1.5806x over previous
//
#include <hip/hip_runtime.h>

// RuleClassifierSNN — forward only, with a runtime interval-dominance gate.
//
// Exact bound: v_{t+1} = 0.8 v_t + d_t (with resets only lowering v) implies
// v_t <= sum_k 0.8^k max(d+) = 5 * max(d+). If 5*max(layer0 drive+) < 1 then
// layer 0 NEVER spikes for ANY id sequence; then layer-1 drive = 0.2*b_lif1,
// and if max(b_lif1+) < 1, layer 1 never spikes either -> spike_acc == 0 ->
// logits == b_cls exactly. The gate is evaluated on-device from the actual
// inputs each call; if it fails, the full fused pipeline (R12, verified) runs.
//
// General path facts (unchanged from R12):
//  * spike(post-reset v) == 0 always -> W_rec vanishes in forward.
//  * layer-0 drive is a V=128-entry lookup table (0.2f-folded) -> LDS.
//  * layer-1 GEMM: spikes {0,1} as i8 in LDS; W as 2-plane i8 fixed point
//    (q1 + q2/252, per-row scale); exact i32 accumulate, P=252*P1+P2 exact.
//  * 256 blocks x 768 thr; waves 0-7 layer-0 chains, waves 8-11 MFMA tiles.

#define T_STEPS 256
#define B_SZ    2048
#define H_SZ    128
#define V_SZ    128
#define E_SZ    64
#define C_SZ    12

typedef __attribute__((ext_vector_type(4))) int   i32x4;
typedef __attribute__((ext_vector_type(4))) float f32x4;

#define OMB  0.2f
#define BETA 0.8f

#define GSTEP  8
#define ROWP   144                  // spike row pitch (bytes)
#define STEPP  (16 * ROWP)          // 2304 B per step tile
#define GROUPP (GSTEP * STEPP)      // 18432 B per group buffer
#define IDP    260                  // ids row pitch (ints)
#define NTHR   768

// ---------------------------------------------------------------------------
// Kernel 1: layer-0 lookup table + bias-init of out + per-block spike bound.
// flagarr[v] = max over h of max(5*max(drive,0), max(b_lif1[h],0)).
__global__ void k_table(const float* __restrict__ emb, const float* __restrict__ W_in,
                        const float* __restrict__ b_in, const float* __restrict__ W_lif0,
                        const float* __restrict__ b_lif0, const float* __restrict__ b_lif1,
                        const float* __restrict__ b_cls,
                        float* __restrict__ table0p, float* __restrict__ flagarr,
                        float* __restrict__ out) {
  __shared__ float x1s[H_SZ];
  __shared__ float red[H_SZ];
  int v = blockIdx.x, h = threadIdx.x;
  float s = b_in[h];
  const float* er = emb + v * E_SZ;
  const float* wr = W_in + h * E_SZ;
#pragma unroll 8
  for (int e = 0; e < E_SZ; ++e) s += er[e] * wr[e];
  x1s[h] = s;
  __syncthreads();
  float t0 = b_lif0[h];
  const float* w0 = W_lif0 + h * H_SZ;
#pragma unroll 8
  for (int i = 0; i < H_SZ; ++i) t0 += x1s[i] * w0[i];
  float td = OMB * t0;
  table0p[v * H_SZ + h] = td;

  // spike-impossibility bound: layer-0 needs 5*max(td+) >= 1;
  // layer-1 (given s0==0) needs 5*0.2*max(b_lif1+) >= 1, i.e. b_lif1 >= 1.
  float q = fmaxf(5.0f * fmaxf(td, 0.0f), fmaxf(b_lif1[h], 0.0f));
  red[h] = q;
  __syncthreads();
#pragma unroll
  for (int off = 64; off > 0; off >>= 1) {
    if (h < off) red[h] = fmaxf(red[h], red[h + off]);
    __syncthreads();
  }
  if (h == 0) flagarr[v] = red[0];

  // out init with bias: 192 elems/block x 128 blocks = 24576 = 2048*12
  int u = v * 192 + h;
  out[u] = b_cls[u % C_SZ];
  if (h < 64) { int u2 = u + 128; out[u2] = b_cls[u2 % C_SZ]; }
}

// ---------------------------------------------------------------------------
// Kernel 2: gate check; if spikes impossible, out is already exact -> return.
// Otherwise full fused layer0 + layer1 + logits (atomicAdd partials).
__launch_bounds__(NTHR, 1)
__global__ void k_fused(const int* __restrict__ ids, const float* __restrict__ table0p,
                        const float* __restrict__ flagarr,
                        const float* __restrict__ W1, const float* __restrict__ b_lif,
                        const float* __restrict__ W_cls, float* __restrict__ out) {
  __shared__ float tbl[V_SZ * H_SZ];                     // 64 KB
  __shared__ int   ids_s[16 * IDP];                      // 16.6 KB
  __shared__ __align__(16) signed char sb[2][GROUPP];    // 36.9 KB
  __shared__ float gate_s;

  const int tid = threadIdx.x;

  // ---- gate ----
  if (tid == 0) {
    const float4* f4 = (const float4*)flagarr;
    float g = 0.0f;
#pragma unroll
    for (int i = 0; i < V_SZ / 4; ++i) {
      float4 x = f4[i];
      g = fmaxf(g, fmaxf(fmaxf(x.x, x.y), fmaxf(x.z, x.w)));
    }
    gate_s = g;
  }
  __syncthreads();
  if (gate_s < 1.0f) return;      // provably zero spikes: out == b_cls already

  const int BG  = blockIdx.x >> 1;      // batches [BG*16, BG*16+16)
  const int NH  = blockIdx.x & 1;       // n in [NH*64, NH*64+64)
  const int lane = tid & 63, w = tid >> 6;
  const int nl = lane & 15, quad = lane >> 4;

  // ---- stage table + ids ----
  {
    const float4* g4 = (const float4*)table0p;
    float4* t4 = (float4*)tbl;
    for (int idx = tid; idx < 4096; idx += NTHR) t4[idx] = g4[idx];
    const int* gi = ids + BG * 16 * T_STEPS;
    for (int idx = tid; idx < 4096; idx += NTHR)
      ids_s[(idx >> 8) * IDP + (idx & 255)] = gi[idx];
  }

  // ---- A-wave state (waves 0-7): batch = w*2 + (lane>>5), 4 h per thread ----
  const int batch = (w * 2 + (lane >> 5)) & 15;
  const int h0 = (lane & 31) * 4;
  const int* idrow = &ids_s[batch * IDP];
  float va[4] = {0.f, 0.f, 0.f, 0.f};

  auto a_group = [&](int gg, int buf) {
    const int tb = gg * GSTEP;
    int idv[GSTEP];
#pragma unroll
    for (int s = 0; s < GSTEP; ++s) idv[s] = idrow[tb + s];     // broadcast
    float4 ta[GSTEP];
#pragma unroll
    for (int s = 0; s < GSTEP; ++s)
      ta[s] = *(const float4*)&tbl[idv[s] * H_SZ + h0];
    signed char* wb = &sb[buf][0] + batch * ROWP + h0;
#pragma unroll
    for (int s = 0; s < GSTEP; ++s) {
      unsigned pa = 0;
      float nv;
      nv = fmaf(BETA, va[0], ta[s].x); pa |= (nv >= 1.f) ? 0x01u : 0u;       va[0] = (nv >= 1.f) ? 0.f : nv;
      nv = fmaf(BETA, va[1], ta[s].y); pa |= (nv >= 1.f) ? 0x0100u : 0u;     va[1] = (nv >= 1.f) ? 0.f : nv;
      nv = fmaf(BETA, va[2], ta[s].z); pa |= (nv >= 1.f) ? 0x010000u : 0u;   va[2] = (nv >= 1.f) ? 0.f : nv;
      nv = fmaf(BETA, va[3], ta[s].w); pa |= (nv >= 1.f) ? 0x01000000u : 0u; va[3] = (nv >= 1.f) ? 0.f : nv;
      *(unsigned*)(wb + s * STEPP) = pa;
    }
  };

  // ---- B-wave constants (waves 8-11): n = NH*64 + (w-8)*16 + nl ----
  i32x4 Wq1[2], Wq2[2];
  float inv2 = 0.f, b1v = 0.f;
  const int n = NH * 64 + ((w - 8) & 3) * 16 + nl;
  if (w >= 8) {
    const float* wrow = W1 + n * H_SZ;
    const float4* w4 = (const float4*)wrow;
    float mx = 1e-20f;
#pragma unroll
    for (int i = 0; i < 32; ++i) {
      float4 x = w4[i];
      mx = fmaxf(mx, fmaxf(fmaxf(fabsf(x.x), fabsf(x.y)), fmaxf(fabsf(x.z), fabsf(x.w))));
    }
    mx *= OMB;
    float S1 = 126.0f / mx, inv1 = 1.0f / S1;
    float S2 = S1 * 252.0f;
    inv2 = 1.0f / S2;
#pragma unroll
    for (int kt = 0; kt < 2; ++kt) {
      int q1w[4] = {0, 0, 0, 0}, q2w[4] = {0, 0, 0, 0};
#pragma unroll
      for (int jj = 0; jj < 16; ++jj) {
        int k = kt * 64 + quad * 16 + jj;
        float ww = OMB * wrow[k];
        float q1 = rintf(ww * S1);
        float r  = fmaf(-q1, inv1, ww);
        float q2 = rintf(r * S2);
        q1w[jj >> 2] |= ((int)q1 & 0xFF) << ((jj & 3) * 8);
        q2w[jj >> 2] |= ((int)q2 & 0xFF) << ((jj & 3) * 8);
      }
      Wq1[kt] = (i32x4){q1w[0], q1w[1], q1w[2], q1w[3]};
      Wq2[kt] = (i32x4){q2w[0], q2w[1], q2w[2], q2w[3]};
    }
    b1v = OMB * b_lif[H_SZ + n];
  }

  f32x4 v1 = {0.f, 0.f, 0.f, 0.f};
  int cnt[4] = {0, 0, 0, 0};
  const i32x4 Z = {0, 0, 0, 0};
  const signed char* const rbase = &sb[0][0] + nl * ROWP + quad * 16;

  __syncthreads();
  if (w < 8) a_group(0, 0);
  __syncthreads();

  for (int g = 0; g < T_STEPS / GSTEP; ++g) {
    if (w < 8) {
      if (g < T_STEPS / GSTEP - 1) a_group(g + 1, (g + 1) & 1);
    } else {
      const signed char* rp = rbase + (g & 1) * GROUPP;
      i32x4 AF0[GSTEP], AF1[GSTEP];
#pragma unroll
      for (int s = 0; s < GSTEP; ++s) {
        AF0[s] = *(const i32x4*)(rp + s * STEPP);
        AF1[s] = *(const i32x4*)(rp + s * STEPP + 64);
      }
      i32x4 Pc1 = __builtin_amdgcn_mfma_i32_16x16x64_i8(AF0[0], Wq1[0], Z, 0, 0, 0);
      Pc1       = __builtin_amdgcn_mfma_i32_16x16x64_i8(AF1[0], Wq1[1], Pc1, 0, 0, 0);
      i32x4 Pc2 = __builtin_amdgcn_mfma_i32_16x16x64_i8(AF0[0], Wq2[0], Z, 0, 0, 0);
      Pc2       = __builtin_amdgcn_mfma_i32_16x16x64_i8(AF1[0], Wq2[1], Pc2, 0, 0, 0);
#pragma unroll
      for (int s = 0; s < GSTEP; ++s) {
        i32x4 Pn1, Pn2;
        if (s < GSTEP - 1) {
          Pn1 = __builtin_amdgcn_mfma_i32_16x16x64_i8(AF0[s + 1], Wq1[0], Z, 0, 0, 0);
          Pn1 = __builtin_amdgcn_mfma_i32_16x16x64_i8(AF1[s + 1], Wq1[1], Pn1, 0, 0, 0);
          Pn2 = __builtin_amdgcn_mfma_i32_16x16x64_i8(AF0[s + 1], Wq2[0], Z, 0, 0, 0);
          Pn2 = __builtin_amdgcn_mfma_i32_16x16x64_i8(AF1[s + 1], Wq2[1], Pn2, 0, 0, 0);
        }
#pragma unroll
        for (int r = 0; r < 4; ++r) {
          int   P   = Pc1[r] * 252 + Pc2[r];         // exact, |P| < 2^23 (i24 mad)
          float cur = fmaf((float)P, inv2, b1v);
          float nv  = fmaf(BETA, v1[r], cur);
          bool  sp  = nv >= 1.0f;
          cnt[r] += sp ? 1 : 0;
          v1[r]  = sp ? 0.0f : nv;
        }
        if (s < GSTEP - 1) { Pc1 = Pn1; Pc2 = Pn2; }
      }
    }
    __syncthreads();
  }

  // ---- partial logits over this block's 64 n (atomicAdd into out) ----
  float* cnt_s = tbl;                       // reuse: 16 rows x 64 cols
  if (w >= 8) {
#pragma unroll
    for (int r = 0; r < 4; ++r)
      cnt_s[(quad * 4 + r) * 64 + ((w - 8) & 3) * 16 + nl] = (float)cnt[r];
  }
  __syncthreads();
  if (tid < 16 * C_SZ) {
    int lb = tid / C_SZ, c = tid - lb * C_SZ;
    const float4* cr = (const float4*)(cnt_s + lb * 64);
    const float4* wr = (const float4*)(W_cls + c * H_SZ + NH * 64);
    float s = 0.0f;
#pragma unroll
    for (int i = 0; i < 16; ++i) {
      float4 a = cr[i], ww = wr[i];
      s += a.x * ww.x + a.y * ww.y + a.z * ww.z + a.w * ww.w;
    }
    atomicAdd(&out[(BG * 16 + lb) * C_SZ + c], s * 0.00390625f);
  }
}

// ---------------------------------------------------------------------------
extern "C" void kernel_launch(void* const* d_in, const int* in_sizes, int n_in,
                              void* d_out, int out_size, void* d_ws, size_t ws_size,
                              hipStream_t stream) {
  (void)in_sizes; (void)n_in; (void)out_size; (void)ws_size;
  const int*   ids   = (const int*)d_in[0];
  const float* emb   = (const float*)d_in[1];
  const float* W_in  = (const float*)d_in[2];
  const float* b_in  = (const float*)d_in[3];
  const float* W_lif = (const float*)d_in[4];
  const float* b_lif = (const float*)d_in[5];
  // d_in[6] (W_rec) provably unused in forward
  const float* W_cls = (const float*)d_in[7];
  const float* b_cls = (const float*)d_in[8];
  float* out = (float*)d_out;

  float* table0p = (float*)d_ws;                       // 64 KB
  float* flagarr = (float*)((char*)d_ws + 65536);      // 512 B

  k_table<<<V_SZ, H_SZ, 0, stream>>>(emb, W_in, b_in, W_lif, b_lif,
                                     b_lif + H_SZ, b_cls, table0p, flagarr, out);
  k_fused<<<256, NTHR, 0, stream>>>(ids, table0p, flagarr,
                                    W_lif + H_SZ * H_SZ, b_lif, W_cls, out);
}